// Round 1
// baseline (7173.276 us; speedup 1.0000x reference)
//
#include <hip/hip_runtime.h>
#include <math.h>

#define D    128
#define NH   8
#define CPH  16
#define RBFD 16
#define SBFD 112
#define LAYERS 3

__device__ __forceinline__ float siluf(float x){ return x / (1.0f + __expf(-x)); }

__device__ __forceinline__ unsigned encodeF(float f){
  unsigned u = __float_as_uint(f);
  return (u & 0x80000000u) ? ~u : (u | 0x80000000u);
}
__device__ __forceinline__ float decodeF(unsigned u){
  return __uint_as_float((u & 0x80000000u) ? (u & 0x7FFFFFFFu) : ~u);
}

// ---------- generic row MLP: Y[M,128] = act(X[gather?][.,DIN] @ W + b) (+ res) ----------
template<int DIN, int ACT, bool GATHER, bool HASB, bool HASRES>
__global__ __launch_bounds__(256) void k_mlp(
    const float* __restrict__ X, const int* __restrict__ gidx,
    const float* __restrict__ W, const float* __restrict__ bias,
    const float* __restrict__ res, float* __restrict__ Y, int M)
{
  __shared__ float Ws[DIN * D];
  __shared__ float Xs[8][DIN];
  for (int i = threadIdx.x; i < DIN * D; i += 256) Ws[i] = W[i];
  const int c0 = threadIdx.x & 63;
  const int r0 = threadIdx.x >> 6;           // 0..3
  for (long tile = blockIdx.x; tile * 8 < (long)M; tile += gridDim.x){
    const long rowBase = tile * 8;
    __syncthreads();
    for (int i = threadIdx.x; i < 8 * DIN; i += 256){
      int r = i / DIN, kk = i - r * DIN;
      long row = rowBase + r;
      float vx = 0.0f;
      if (row < M){
        long srow = GATHER ? (long)gidx[row] : row;
        vx = X[srow * DIN + kk];
      }
      Xs[r][kk] = vx;
    }
    __syncthreads();
    float a00 = 0.f, a01 = 0.f, a10 = 0.f, a11 = 0.f;
    #pragma unroll 8
    for (int k = 0; k < DIN; k++){
      float w0 = Ws[k * D + c0];
      float w1 = Ws[k * D + c0 + 64];
      float x0 = Xs[r0][k];
      float x1 = Xs[r0 + 4][k];
      a00 += x0 * w0; a01 += x0 * w1;
      a10 += x1 * w0; a11 += x1 * w1;
    }
    long row = rowBase + r0;
    if (row < M){
      float v0 = a00, v1 = a01;
      if (HASB){ v0 += bias[c0]; v1 += bias[c0 + 64]; }
      if (ACT){ v0 = siluf(v0); v1 = siluf(v1); }
      if (HASRES){ v0 += res[row * D + c0]; v1 += res[row * D + c0 + 64]; }
      Y[row * D + c0] = v0; Y[row * D + c0 + 64] = v1;
    }
    row = rowBase + r0 + 4;
    if (row < M){
      float v0 = a10, v1 = a11;
      if (HASB){ v0 += bias[c0]; v1 += bias[c0 + 64]; }
      if (ACT){ v0 = siluf(v0); v1 = siluf(v1); }
      if (HASRES){ v0 += res[row * D + c0]; v1 += res[row * D + c0 + 64]; }
      Y[row * D + c0] = v0; Y[row * D + c0 + 64] = v1;
    }
  }
}

// ---------- scatter rows: Yat[idx[r],c] += X[r,c] ----------
__global__ void k_scatter(const float* __restrict__ X, const int* __restrict__ idx,
                          float* __restrict__ Yat, int M)
{
  long total = (long)M * D;
  for (long i = (long)blockIdx.x * 256 + threadIdx.x; i < total; i += (long)gridDim.x * 256){
    long row = i >> 7; int c = (int)(i & 127);
    atomicAdd(&Yat[(long)idx[row] * D + c], X[i]);
  }
}

// ---------- rbf gate: Y[r,c] = Hin[r,c] * (rbf[r,:] @ Wr)[c] ----------
__global__ void k_rbf_gate(const float* __restrict__ Hin, const float* __restrict__ rbf,
                           const float* __restrict__ Wr, float* __restrict__ Y, int M)
{
  __shared__ float Wrs[RBFD * D];
  for (int i = threadIdx.x; i < RBFD * D; i += 256) Wrs[i] = Wr[i];
  __syncthreads();
  long total = (long)M * D;
  for (long i = (long)blockIdx.x * 256 + threadIdx.x; i < total; i += (long)gridDim.x * 256){
    long row = i >> 7; int c = (int)(i & 127);
    const float* rb = rbf + row * RBFD;
    float g = 0.f;
    #pragma unroll
    for (int r = 0; r < RBFD; r++) g += rb[r] * Wrs[r * D + c];
    Y[i] = Hin[i] * g;
  }
}

// ---------- logit + segment max ----------
__global__ void k_logit_max(const float* __restrict__ q, const float* __restrict__ kk,
                            const float* __restrict__ ek, const int* __restrict__ srcA,
                            const int* __restrict__ dstA, float* __restrict__ logit,
                            unsigned* __restrict__ mEnc, int E_)
{
  long total = (long)E_ * NH;
  for (long i = (long)blockIdx.x * 256 + threadIdx.x; i < total; i += (long)gridDim.x * 256){
    long e = i >> 3; int h = (int)(i & 7);
    int s = srcA[e], d = dstA[e];
    const float4* qv = (const float4*)(q  + (long)d * D + h * CPH);
    const float4* kv = (const float4*)(kk + (long)s * D + h * CPH);
    const float4* ev = (const float4*)(ek + e * D + h * CPH);
    float acc = 0.f;
    #pragma unroll
    for (int j = 0; j < 4; j++){
      float4 a = qv[j], b = kv[j], c = ev[j];
      acc += a.x*(b.x+c.x) + a.y*(b.y+c.y) + a.z*(b.z+c.z) + a.w*(b.w+c.w);
    }
    float l = acc * 0.25f;   // / sqrt(16)
    logit[i] = l;
    atomicMax(&mEnc[(long)d * NH + h], encodeF(l));
  }
}

// ---------- exp(logit - m) and denominator ----------
__global__ void k_exp_sum(float* __restrict__ logit, const unsigned* __restrict__ mEnc,
                          const int* __restrict__ dstA, float* __restrict__ denom, int E_)
{
  long total = (long)E_ * NH;
  for (long i = (long)blockIdx.x * 256 + threadIdx.x; i < total; i += (long)gridDim.x * 256){
    long e = i >> 3; int h = (int)(i & 7);
    int d = dstA[e];
    float m = decodeF(mEnc[(long)d * NH + h]);
    float ex = __expf(logit[i] - m);
    logit[i] = ex;
    atomicAdd(&denom[(long)d * NH + h], ex);
  }
}

// ---------- message + scatter to h ----------
__global__ void k_message(const float* __restrict__ v, const float* __restrict__ ek,
                          const float* __restrict__ sw, const float* __restrict__ ex,
                          const float* __restrict__ denom, const int* __restrict__ srcA,
                          const int* __restrict__ dstA, float* __restrict__ hout, int E_)
{
  long total = (long)E_ * D;
  for (long i = (long)blockIdx.x * 256 + threadIdx.x; i < total; i += (long)gridDim.x * 256){
    long e = i >> 7; int c = (int)(i & 127); int h = c >> 4;
    int s = srcA[e], d = dstA[e];
    float al = ex[e * NH + h] / (denom[(long)d * NH + h] + 1e-16f);
    float val = (v[(long)s * D + c] + ek[i]) * al * sw[i];
    atomicAdd(&hout[(long)d * D + c], val);
  }
}

// ---------- graph norm ----------
__global__ void k_count(const int* __restrict__ batch, int* __restrict__ cnt, int M)
{
  for (long i = (long)blockIdx.x * 256 + threadIdx.x; i < M; i += (long)gridDim.x * 256)
    atomicAdd(&cnt[batch[i]], 1);
}

__global__ void k_norm_stats(const float* __restrict__ Hin, const int* __restrict__ batch,
                             double* __restrict__ sums, double* __restrict__ sumsq, int M)
{
  int lane = threadIdx.x & 63;
  long wave = ((long)blockIdx.x * blockDim.x + threadIdx.x) >> 6;
  long nw = ((long)gridDim.x * blockDim.x) >> 6;
  for (long row = wave; row < M; row += nw){
    float x0 = Hin[row * D + lane], x1 = Hin[row * D + lane + 64];
    float s = x0 + x1;
    float qq = x0 * x0 + x1 * x1;
    for (int off = 32; off > 0; off >>= 1){
      s  += __shfl_down(s, off, 64);
      qq += __shfl_down(qq, off, 64);
    }
    if (lane == 0){
      int g = batch[row];
      atomicAdd(&sums[g], (double)s);
      atomicAdd(&sumsq[g], (double)qq);
    }
  }
}

__global__ void k_norm_final(const double* __restrict__ sums, const double* __restrict__ sumsq,
                             const int* __restrict__ cnt, float* __restrict__ meanG,
                             float* __restrict__ rstdG)
{
  int g = threadIdx.x;
  double c = (double)cnt[g] * (double)D;
  double mean = sums[g] / c;
  double var = sumsq[g] / c - mean * mean;
  meanG[g] = (float)mean;
  rstdG[g] = (float)(1.0 / sqrt(var + 1e-8));
}

__global__ void k_norm_apply(float* __restrict__ Hio, const int* __restrict__ batch,
                             const float* __restrict__ meanG, const float* __restrict__ rstdG, int M)
{
  long total = (long)M * D;
  for (long i = (long)blockIdx.x * 256 + threadIdx.x; i < total; i += (long)gridDim.x * 256){
    long row = i >> 7;
    int g = batch[row];
    Hio[i] = (Hio[i] - meanG[g]) * rstdG[g];
  }
}

// ---------- readout tail: results[r] += A2[r,:] @ w3 + b3 ----------
__global__ void k_dot3(const float* __restrict__ A2, const float* __restrict__ w3,
                       const float* __restrict__ b3, float* __restrict__ results, int M)
{
  int lane = threadIdx.x & 63;
  long wave = ((long)blockIdx.x * blockDim.x + threadIdx.x) >> 6;
  long nw = ((long)gridDim.x * blockDim.x) >> 6;
  for (long row = wave; row < M; row += nw){
    float a = A2[row * D + lane] * w3[lane] + A2[row * D + lane + 64] * w3[lane + 64];
    for (int off = 32; off > 0; off >>= 1) a += __shfl_down(a, off, 64);
    if (lane == 0) results[row] += a + b3[0];
  }
}

// ---------- final: out[g] += results[a] / L ----------
__global__ void k_final(const float* __restrict__ results, const int* __restrict__ ab,
                        float* __restrict__ out, int A_)
{
  int i = blockIdx.x * 256 + threadIdx.x;
  if (i < A_) atomicAdd(&out[ab[i]], results[i] / 3.0f);
}

// ---------- fold w2@we (per layer), b2@we ----------
__global__ void k_w2e(const float* __restrict__ w2, const float* __restrict__ we,
                      float* __restrict__ W2e)
{
  int i = blockIdx.x >> 7;    // layer
  int r = blockIdx.x & 127;   // k-row
  int c = threadIdx.x;
  const float* w2p = w2 + (size_t)i * D * D + (size_t)r * D;
  const float* wep = we + (size_t)i * D * D;
  float acc = 0.f;
  for (int j = 0; j < D; j++) acc += w2p[j] * wep[j * D + c];
  W2e[(size_t)i * D * D + (size_t)r * D + c] = acc;
}

__global__ void k_b2e(const float* __restrict__ b2, const float* __restrict__ we,
                      float* __restrict__ B2e)
{
  int i = blockIdx.x; int c = threadIdx.x;
  float acc = 0.f;
  for (int j = 0; j < D; j++) acc += b2[(size_t)i * D + j] * we[(size_t)i * D * D + j * D + c];
  B2e[(size_t)i * D + c] = acc;
}

extern "C" void kernel_launch(void* const* d_in, const int* in_sizes, int n_in,
                              void* d_out, int out_size, void* d_ws, size_t ws_size,
                              hipStream_t stream)
{
  const float* x          = (const float*)d_in[0];
  const float* node_rbf   = (const float*)d_in[1];
  const float* edge_sbf   = (const float*)d_in[2];
  const int*   edge_index = (const int*)d_in[3];
  const int*   pair_idx   = (const int*)d_in[4];
  const int*   eidx0      = (const int*)d_in[5];
  const int*   atom_batch = (const int*)d_in[6];
  const int*   batch      = (const int*)d_in[7];
  const float* edgenn_w1  = (const float*)d_in[8];
  const float* edgenn_b1  = (const float*)d_in[9];
  const float* edgenn_w2  = (const float*)d_in[10];
  const float* edgenn_b2  = (const float*)d_in[11];
  const float* conv_wq    = (const float*)d_in[12];
  const float* conv_wk    = (const float*)d_in[13];
  const float* conv_wv    = (const float*)d_in[14];
  const float* conv_we    = (const float*)d_in[15];
  const float* conv_wsbf  = (const float*)d_in[16];
  const float* conv_bsbf  = (const float*)d_in[17];
  const float* conv_wrbf  = (const float*)d_in[18];
  const float* dense_w    = (const float*)d_in[19];
  const float* dense_b    = (const float*)d_in[20];
  const float* bf_w       = (const float*)d_in[21];
  const float* bf_b       = (const float*)d_in[22];
  const float* af_w       = (const float*)d_in[23];
  const float* af_b       = (const float*)d_in[24];
  const float* read_wrbf  = (const float*)d_in[25];
  const float* read_w1    = (const float*)d_in[26];
  const float* read_b1    = (const float*)d_in[27];
  const float* read_w2    = (const float*)d_in[28];
  const float* read_b2    = (const float*)d_in[29];
  const float* read_w3    = (const float*)d_in[30];
  const float* read_b3    = (const float*)d_in[31];

  const int N = in_sizes[0] / D;
  const int E = in_sizes[4];
  const int A = in_sizes[6];
  const int G = out_size;

  char* p = (char*)d_ws;
  auto carve = [&](size_t bytes)->char*{ char* r = p; p += (bytes + 255) & ~(size_t)255; return r; };
  float*    EbufA   = (float*)carve((size_t)E * D * 4);   // hidden, then sw
  float*    EbufB   = (float*)carve((size_t)E * D * 4);   // ek
  float*    ping0   = (float*)carve((size_t)N * D * 4);
  float*    ping1   = (float*)carve((size_t)N * D * 4);
  float*    bq      = (float*)carve((size_t)N * D * 4);   // q, then h
  float*    bk      = (float*)carve((size_t)N * D * 4);   // k, then MLP temp
  float*    bv      = (float*)carve((size_t)N * D * 4);   // v, then readout gate
  float*    bufAtoms= (float*)carve((size_t)A * D * 4);
  float*    a1      = (float*)carve((size_t)A * D * 4);
  float*    a2      = (float*)carve((size_t)A * D * 4);
  float*    logitB  = (float*)carve((size_t)E * NH * 4);
  unsigned* mEnc    = (unsigned*)carve((size_t)N * NH * 4);
  float*    denom   = (float*)carve((size_t)N * NH * 4);
  float*    results = (float*)carve((size_t)A * 4);
  double*   sumG    = (double*)carve((size_t)G * 8);
  double*   sumsqG  = (double*)carve((size_t)G * 8);
  int*      cntG    = (int*)carve((size_t)G * 4);
  float*    meanG   = (float*)carve((size_t)G * 4);
  float*    rstdG   = (float*)carve((size_t)G * 4);
  float*    W2e     = (float*)carve((size_t)LAYERS * D * D * 4);
  float*    B2e     = (float*)carve((size_t)LAYERS * D * 4);

  const int* srcA = edge_index;
  const int* dstA = edge_index + E;

  auto ew_grid = [](long total){ long b = (total + 255) / 256; return (int)(b < 4096 ? b : 4096); };
  auto mlp_grid = [](int M){ int t = (M + 7) / 8; return t < 1024 ? t : 1024; };

  // one-time per launch
  hipMemsetAsync(cntG, 0, (size_t)G * 4, stream);
  hipMemsetAsync(results, 0, (size_t)A * 4, stream);
  hipMemsetAsync(d_out, 0, (size_t)G * 4, stream);
  k_count<<<ew_grid(N), 256, 0, stream>>>(batch, cntG, N);
  k_w2e<<<LAYERS * D, D, 0, stream>>>(edgenn_w2, conv_we, W2e);
  k_b2e<<<LAYERS, D, 0, stream>>>(edgenn_b2, conv_we, B2e);

  auto readout = [&](int i, const float* hbuf){
    k_rbf_gate<<<ew_grid((long)N * D), 256, 0, stream>>>(hbuf, node_rbf, read_wrbf + (size_t)i * RBFD * D, bv, N);
    hipMemsetAsync(bufAtoms, 0, (size_t)A * D * 4, stream);
    k_scatter<<<ew_grid((long)N * D), 256, 0, stream>>>(bv, eidx0, bufAtoms, N);
    k_mlp<D,1,false,true,false><<<mlp_grid(A),256,0,stream>>>(bufAtoms, nullptr, read_w1 + (size_t)i*D*D, read_b1 + (size_t)i*D, nullptr, a1, A);
    k_mlp<D,1,false,true,false><<<mlp_grid(A),256,0,stream>>>(a1, nullptr, read_w2 + (size_t)i*D*D, read_b2 + (size_t)i*D, nullptr, a2, A);
    k_dot3<<<((A * 64 + 255) / 256), 256, 0, stream>>>(a2, read_w3 + (size_t)i * D, read_b3 + i, results, A);
  };

  readout(0, x);

  const float* cur = x;
  float* pp[2] = {ping0, ping1};
  for (int i = 0; i < LAYERS; i++){
    float* nxt = pp[i & 1];
    const size_t oDD = (size_t)i * D * D;
    // atoms_rep = segsum(cur, eidx0)
    hipMemsetAsync(bufAtoms, 0, (size_t)A * D * 4, stream);
    k_scatter<<<ew_grid((long)N * D), 256, 0, stream>>>(cur, eidx0, bufAtoms, N);
    // hidden = silu(atoms_rep[pair_idx] @ w1 + b1)
    k_mlp<D,1,true,true,false><<<mlp_grid(E),256,0,stream>>>(bufAtoms, pair_idx, edgenn_w1 + oDD, edgenn_b1 + (size_t)i*D, nullptr, EbufA, E);
    // ek = hidden @ (w2@we) + b2@we
    k_mlp<D,0,false,true,false><<<mlp_grid(E),256,0,stream>>>(EbufA, nullptr, W2e + oDD, B2e + (size_t)i*D, nullptr, EbufB, E);
    // q, k, v
    k_mlp<D,0,false,false,false><<<mlp_grid(N),256,0,stream>>>(cur, nullptr, conv_wq + oDD, nullptr, nullptr, bq, N);
    k_mlp<D,0,false,false,false><<<mlp_grid(N),256,0,stream>>>(cur, nullptr, conv_wk + oDD, nullptr, nullptr, bk, N);
    k_mlp<D,0,false,false,false><<<mlp_grid(N),256,0,stream>>>(cur, nullptr, conv_wv + oDD, nullptr, nullptr, bv, N);
    // attention softmax
    hipMemsetAsync(mEnc, 0, (size_t)N * NH * 4, stream);
    k_logit_max<<<ew_grid((long)E * NH), 256, 0, stream>>>(bq, bk, EbufB, srcA, dstA, logitB, mEnc, E);
    hipMemsetAsync(denom, 0, (size_t)N * NH * 4, stream);
    k_exp_sum<<<ew_grid((long)E * NH), 256, 0, stream>>>(logitB, mEnc, dstA, denom, E);
    // sw = edge_sbf @ wsbf + bsbf  (reuse EbufA)
    k_mlp<SBFD,0,false,true,false><<<mlp_grid(E),256,0,stream>>>(edge_sbf, nullptr, conv_wsbf + (size_t)i*SBFD*D, conv_bsbf + (size_t)i*D, nullptr, EbufA, E);
    // h = segsum((v[src]+ek)*alpha*sw) into bq
    hipMemsetAsync(bq, 0, (size_t)N * D * 4, stream);
    k_message<<<ew_grid((long)E * D), 256, 0, stream>>>(bv, EbufB, EbufA, logitB, denom, srcA, dstA, bq, E);
    // rbf gate (in place)
    k_rbf_gate<<<ew_grid((long)N * D), 256, 0, stream>>>(bq, node_rbf, conv_wrbf + (size_t)i*RBFD*D, bq, N);
    // graph norm
    hipMemsetAsync(sumG, 0, (size_t)G * 8, stream);
    hipMemsetAsync(sumsqG, 0, (size_t)G * 8, stream);
    k_norm_stats<<<4096, 256, 0, stream>>>(bq, batch, sumG, sumsqG, N);
    k_norm_final<<<1, G, 0, stream>>>(sumG, sumsqG, cntG, meanG, rstdG);
    k_norm_apply<<<ew_grid((long)N * D), 256, 0, stream>>>(bq, batch, meanG, rstdG, N);
    // bf residual block
    k_mlp<D,1,false,true,false><<<mlp_grid(N),256,0,stream>>>(bq, nullptr, bf_w + (size_t)i*2*D*D, bf_b + (size_t)i*2*D, nullptr, bk, N);
    k_mlp<D,1,false,true,true ><<<mlp_grid(N),256,0,stream>>>(bk, nullptr, bf_w + (size_t)i*2*D*D + D*D, bf_b + (size_t)i*2*D + D, bq, bq, N);
    // dense + res0
    k_mlp<D,1,false,true,true ><<<mlp_grid(N),256,0,stream>>>(bq, nullptr, dense_w + oDD, dense_b + (size_t)i*D, cur, nxt, N);
    // af residual blocks
    k_mlp<D,1,false,true,false><<<mlp_grid(N),256,0,stream>>>(nxt, nullptr, af_w + (size_t)i*4*D*D,         af_b + (size_t)i*4*D,       nullptr, bk, N);
    k_mlp<D,1,false,true,true ><<<mlp_grid(N),256,0,stream>>>(bk, nullptr, af_w + (size_t)i*4*D*D + D*D,   af_b + (size_t)i*4*D + D,   nxt, nxt, N);
    k_mlp<D,1,false,true,false><<<mlp_grid(N),256,0,stream>>>(nxt, nullptr, af_w + (size_t)i*4*D*D + 2*D*D, af_b + (size_t)i*4*D + 2*D, nullptr, bk, N);
    k_mlp<D,1,false,true,true ><<<mlp_grid(N),256,0,stream>>>(bk, nullptr, af_w + (size_t)i*4*D*D + 3*D*D, af_b + (size_t)i*4*D + 3*D, nxt, nxt, N);
    // readout
    readout(i + 1, nxt);
    cur = nxt;
  }
  k_final<<<(A + 255) / 256, 256, 0, stream>>>(results, atom_batch, (float*)d_out, A);
}

// Round 2
// 3948.482 us; speedup vs baseline: 1.8167x; 1.8167x over previous
//
#include <hip/hip_runtime.h>
#include <math.h>

#define D    128
#define NH   8
#define CPH  16
#define RBFD 16
#define SBFD 112
#define LAYERS 3

typedef __attribute__((ext_vector_type(8))) short bf16x8;
typedef __attribute__((ext_vector_type(4))) float f32x4;

__device__ __forceinline__ float siluf(float x){ return x / (1.0f + __expf(-x)); }

__device__ __forceinline__ short f2bf(float f){
  union { float f; unsigned u; } v; v.f = f;
  unsigned r = v.u + 0x7FFFu + ((v.u >> 16) & 1u);   // RNE
  return (short)(r >> 16);
}

__device__ __forceinline__ unsigned encodeF(float f){
  unsigned u = __float_as_uint(f);
  return (u & 0x80000000u) ? ~u : (u | 0x80000000u);
}
__device__ __forceinline__ float decodeF(unsigned u){
  return __uint_as_float((u & 0x80000000u) ? (u & 0x7FFFFFFFu) : ~u);
}

// ---------- MFMA GEMM: Y[M,128] = epilogue(X[gather?][.,DIN] @ W[DIN,128]) ----------
// block = 256 threads = 4 waves; each block tile = 64 rows x 128 cols (16 rows/wave).
// W is bf16-converted + transposed into LDS once; B-fragments hoisted to registers,
// so the M-loop touches no LDS. A loaded fp32 from global, converted in-register.
template<int DIN, int ACT, bool GATHER, bool HASB, bool HASRES>
__global__ __launch_bounds__(256, 2) void k_gemm(
    const float* __restrict__ X, const int* __restrict__ gidx,
    const float* __restrict__ W, const float* __restrict__ bias,
    const float* res, float* __restrict__ Y, int M)
{
  __shared__ short Wt[128 * 128];          // transposed bf16 weights: Wt[col][k]
  if (DIN < 128){
    for (int i = threadIdx.x; i < 128 * 128; i += 256) Wt[i] = 0;
    __syncthreads();
  }
  for (int i = threadIdx.x; i < DIN * 128; i += 256){
    int k = i >> 7, c = i & 127;
    Wt[c * 128 + k] = f2bf(W[i]);
  }
  __syncthreads();

  const int lane = threadIdx.x & 63;
  const int wave = threadIdx.x >> 6;       // 0..3
  const int col0 = lane & 15;
  const int kg   = lane >> 4;              // 0..3

  bf16x8 Bf[8][4];                         // [colTile][kStep]
  #pragma unroll
  for (int ct = 0; ct < 8; ct++)
    #pragma unroll
    for (int s = 0; s < 4; s++)
      Bf[ct][s] = *(const bf16x8*)&Wt[(ct * 16 + col0) * 128 + s * 32 + kg * 8];

  float bs[8];
  if (HASB){
    #pragma unroll
    for (int ct = 0; ct < 8; ct++) bs[ct] = bias[ct * 16 + col0];
  }

  const long tiles = ((long)M + 63) >> 6;
  for (long t = blockIdx.x; t < tiles; t += gridDim.x){
    const long rbase = t * 64 + wave * 16;
    const long arow  = rbase + col0;       // A-row this lane supplies
    long srow = 0;
    if (arow < M) srow = GATHER ? (long)gidx[arow] : arow;
    const float* Xp = X + srow * DIN;

    bf16x8 Af[4];
    #pragma unroll
    for (int s = 0; s < 4; s++){
      const int kb = s * 32 + kg * 8;
      bf16x8 a;
      if (DIN == 128 || kb + 8 <= DIN){
        float4 lo = *(const float4*)(Xp + kb);
        float4 hi = *(const float4*)(Xp + kb + 4);
        a[0]=f2bf(lo.x); a[1]=f2bf(lo.y); a[2]=f2bf(lo.z); a[3]=f2bf(lo.w);
        a[4]=f2bf(hi.x); a[5]=f2bf(hi.y); a[6]=f2bf(hi.z); a[7]=f2bf(hi.w);
      } else {
        #pragma unroll
        for (int j = 0; j < 8; j++) a[j] = 0;
      }
      Af[s] = a;
    }

    f32x4 acc[8];
    #pragma unroll
    for (int ct = 0; ct < 8; ct++){ acc[ct][0]=0.f; acc[ct][1]=0.f; acc[ct][2]=0.f; acc[ct][3]=0.f; }
    #pragma unroll
    for (int ct = 0; ct < 8; ct++)
      #pragma unroll
      for (int s = 0; s < 4; s++)
        acc[ct] = __builtin_amdgcn_mfma_f32_16x16x32_bf16(Af[s], Bf[ct][s], acc[ct], 0, 0, 0);

    // epilogue: C/D layout col = lane&15, row = kg*4 + reg
    #pragma unroll
    for (int ct = 0; ct < 8; ct++){
      const int c = ct * 16 + col0;
      #pragma unroll
      for (int r = 0; r < 4; r++){
        const long orow = rbase + kg * 4 + r;
        if (orow < M){
          float v = acc[ct][r];
          if (HASB) v += bs[ct];
          if (ACT)  v = siluf(v);
          if (HASRES) v += res[orow * D + c];
          Y[orow * D + c] = v;
        }
      }
    }
  }
}

// ---------- scatter rows: Yat[idx[r],c] += X[r,c] ----------
__global__ void k_scatter(const float* __restrict__ X, const int* __restrict__ idx,
                          float* __restrict__ Yat, int M)
{
  long total = (long)M * D;
  for (long i = (long)blockIdx.x * 256 + threadIdx.x; i < total; i += (long)gridDim.x * 256){
    long row = i >> 7; int c = (int)(i & 127);
    atomicAdd(&Yat[(long)idx[row] * D + c], X[i]);
  }
}

// ---------- rbf gate: Y[r,c] = Hin[r,c] * (rbf[r,:] @ Wr)[c] ----------
__global__ void k_rbf_gate(const float* __restrict__ Hin, const float* __restrict__ rbf,
                           const float* __restrict__ Wr, float* __restrict__ Y, int M)
{
  __shared__ float Wrs[RBFD * D];
  for (int i = threadIdx.x; i < RBFD * D; i += 256) Wrs[i] = Wr[i];
  __syncthreads();
  long total = (long)M * D;
  for (long i = (long)blockIdx.x * 256 + threadIdx.x; i < total; i += (long)gridDim.x * 256){
    long row = i >> 7; int c = (int)(i & 127);
    const float* rb = rbf + row * RBFD;
    float g = 0.f;
    #pragma unroll
    for (int r = 0; r < RBFD; r++) g += rb[r] * Wrs[r * D + c];
    Y[i] = Hin[i] * g;
  }
}

// ---------- logit + segment max ----------
__global__ void k_logit_max(const float* __restrict__ q, const float* __restrict__ kk,
                            const float* __restrict__ ek, const int* __restrict__ srcA,
                            const int* __restrict__ dstA, float* __restrict__ logit,
                            unsigned* __restrict__ mEnc, int E_)
{
  long total = (long)E_ * NH;
  for (long i = (long)blockIdx.x * 256 + threadIdx.x; i < total; i += (long)gridDim.x * 256){
    long e = i >> 3; int h = (int)(i & 7);
    int s = srcA[e], d = dstA[e];
    const float4* qv = (const float4*)(q  + (long)d * D + h * CPH);
    const float4* kv = (const float4*)(kk + (long)s * D + h * CPH);
    const float4* ev = (const float4*)(ek + e * D + h * CPH);
    float acc = 0.f;
    #pragma unroll
    for (int j = 0; j < 4; j++){
      float4 a = qv[j], b = kv[j], c = ev[j];
      acc += a.x*(b.x+c.x) + a.y*(b.y+c.y) + a.z*(b.z+c.z) + a.w*(b.w+c.w);
    }
    float l = acc * 0.25f;   // / sqrt(16)
    logit[i] = l;
    atomicMax(&mEnc[(long)d * NH + h], encodeF(l));
  }
}

// ---------- exp(logit - m) and denominator ----------
__global__ void k_exp_sum(float* __restrict__ logit, const unsigned* __restrict__ mEnc,
                          const int* __restrict__ dstA, float* __restrict__ denom, int E_)
{
  long total = (long)E_ * NH;
  for (long i = (long)blockIdx.x * 256 + threadIdx.x; i < total; i += (long)gridDim.x * 256){
    long e = i >> 3; int h = (int)(i & 7);
    int d = dstA[e];
    float m = decodeF(mEnc[(long)d * NH + h]);
    float ex = __expf(logit[i] - m);
    logit[i] = ex;
    atomicAdd(&denom[(long)d * NH + h], ex);
  }
}

// ---------- message + scatter to h ----------
__global__ void k_message(const float* __restrict__ v, const float* __restrict__ ek,
                          const float* __restrict__ sw, const float* __restrict__ ex,
                          const float* __restrict__ denom, const int* __restrict__ srcA,
                          const int* __restrict__ dstA, float* __restrict__ hout, int E_)
{
  long total = (long)E_ * D;
  for (long i = (long)blockIdx.x * 256 + threadIdx.x; i < total; i += (long)gridDim.x * 256){
    long e = i >> 7; int c = (int)(i & 127); int h = c >> 4;
    int s = srcA[e], d = dstA[e];
    float al = ex[e * NH + h] / (denom[(long)d * NH + h] + 1e-16f);
    float val = (v[(long)s * D + c] + ek[i]) * al * sw[i];
    atomicAdd(&hout[(long)d * D + c], val);
  }
}

// ---------- graph norm ----------
__global__ void k_count(const int* __restrict__ batch, int* __restrict__ cnt, int M)
{
  for (long i = (long)blockIdx.x * 256 + threadIdx.x; i < M; i += (long)gridDim.x * 256)
    atomicAdd(&cnt[batch[i]], 1);
}

__global__ void k_norm_stats(const float* __restrict__ Hin, const int* __restrict__ batch,
                             double* __restrict__ sums, double* __restrict__ sumsq, int M)
{
  int lane = threadIdx.x & 63;
  long wave = ((long)blockIdx.x * blockDim.x + threadIdx.x) >> 6;
  long nw = ((long)gridDim.x * blockDim.x) >> 6;
  for (long row = wave; row < M; row += nw){
    float x0 = Hin[row * D + lane], x1 = Hin[row * D + lane + 64];
    float s = x0 + x1;
    float qq = x0 * x0 + x1 * x1;
    for (int off = 32; off > 0; off >>= 1){
      s  += __shfl_down(s, off, 64);
      qq += __shfl_down(qq, off, 64);
    }
    if (lane == 0){
      int g = batch[row];
      atomicAdd(&sums[g], (double)s);
      atomicAdd(&sumsq[g], (double)qq);
    }
  }
}

__global__ void k_norm_final(const double* __restrict__ sums, const double* __restrict__ sumsq,
                             const int* __restrict__ cnt, float* __restrict__ meanG,
                             float* __restrict__ rstdG)
{
  int g = threadIdx.x;
  double c = (double)cnt[g] * (double)D;
  double mean = sums[g] / c;
  double var = sumsq[g] / c - mean * mean;
  meanG[g] = (float)mean;
  rstdG[g] = (float)(1.0 / sqrt(var + 1e-8));
}

__global__ void k_norm_apply(float* __restrict__ Hio, const int* __restrict__ batch,
                             const float* __restrict__ meanG, const float* __restrict__ rstdG, int M)
{
  long total = (long)M * D;
  for (long i = (long)blockIdx.x * 256 + threadIdx.x; i < total; i += (long)gridDim.x * 256){
    long row = i >> 7;
    int g = batch[row];
    Hio[i] = (Hio[i] - meanG[g]) * rstdG[g];
  }
}

// ---------- readout tail: results[r] += A2[r,:] @ w3 + b3 ----------
__global__ void k_dot3(const float* __restrict__ A2, const float* __restrict__ w3,
                       const float* __restrict__ b3, float* __restrict__ results, int M)
{
  int lane = threadIdx.x & 63;
  long wave = ((long)blockIdx.x * blockDim.x + threadIdx.x) >> 6;
  long nw = ((long)gridDim.x * blockDim.x) >> 6;
  for (long row = wave; row < M; row += nw){
    float a = A2[row * D + lane] * w3[lane] + A2[row * D + lane + 64] * w3[lane + 64];
    for (int off = 32; off > 0; off >>= 1) a += __shfl_down(a, off, 64);
    if (lane == 0) results[row] += a + b3[0];
  }
}

// ---------- final: out[g] += results[a] / L ----------
__global__ void k_final(const float* __restrict__ results, const int* __restrict__ ab,
                        float* __restrict__ out, int A_)
{
  int i = blockIdx.x * 256 + threadIdx.x;
  if (i < A_) atomicAdd(&out[ab[i]], results[i] / 3.0f);
}

// ---------- fold w2@we (per layer), b2@we ----------
__global__ void k_w2e(const float* __restrict__ w2, const float* __restrict__ we,
                      float* __restrict__ W2e)
{
  int i = blockIdx.x >> 7;    // layer
  int r = blockIdx.x & 127;   // k-row
  int c = threadIdx.x;
  const float* w2p = w2 + (size_t)i * D * D + (size_t)r * D;
  const float* wep = we + (size_t)i * D * D;
  float acc = 0.f;
  for (int j = 0; j < D; j++) acc += w2p[j] * wep[j * D + c];
  W2e[(size_t)i * D * D + (size_t)r * D + c] = acc;
}

__global__ void k_b2e(const float* __restrict__ b2, const float* __restrict__ we,
                      float* __restrict__ B2e)
{
  int i = blockIdx.x; int c = threadIdx.x;
  float acc = 0.f;
  for (int j = 0; j < D; j++) acc += b2[(size_t)i * D + j] * we[(size_t)i * D * D + j * D + c];
  B2e[(size_t)i * D + c] = acc;
}

extern "C" void kernel_launch(void* const* d_in, const int* in_sizes, int n_in,
                              void* d_out, int out_size, void* d_ws, size_t ws_size,
                              hipStream_t stream)
{
  const float* x          = (const float*)d_in[0];
  const float* node_rbf   = (const float*)d_in[1];
  const float* edge_sbf   = (const float*)d_in[2];
  const int*   edge_index = (const int*)d_in[3];
  const int*   pair_idx   = (const int*)d_in[4];
  const int*   eidx0      = (const int*)d_in[5];
  const int*   atom_batch = (const int*)d_in[6];
  const int*   batch      = (const int*)d_in[7];
  const float* edgenn_w1  = (const float*)d_in[8];
  const float* edgenn_b1  = (const float*)d_in[9];
  const float* edgenn_w2  = (const float*)d_in[10];
  const float* edgenn_b2  = (const float*)d_in[11];
  const float* conv_wq    = (const float*)d_in[12];
  const float* conv_wk    = (const float*)d_in[13];
  const float* conv_wv    = (const float*)d_in[14];
  const float* conv_we    = (const float*)d_in[15];
  const float* conv_wsbf  = (const float*)d_in[16];
  const float* conv_bsbf  = (const float*)d_in[17];
  const float* conv_wrbf  = (const float*)d_in[18];
  const float* dense_w    = (const float*)d_in[19];
  const float* dense_b    = (const float*)d_in[20];
  const float* bf_w       = (const float*)d_in[21];
  const float* bf_b       = (const float*)d_in[22];
  const float* af_w       = (const float*)d_in[23];
  const float* af_b       = (const float*)d_in[24];
  const float* read_wrbf  = (const float*)d_in[25];
  const float* read_w1    = (const float*)d_in[26];
  const float* read_b1    = (const float*)d_in[27];
  const float* read_w2    = (const float*)d_in[28];
  const float* read_b2    = (const float*)d_in[29];
  const float* read_w3    = (const float*)d_in[30];
  const float* read_b3    = (const float*)d_in[31];

  const int N = in_sizes[0] / D;
  const int E = in_sizes[4];
  const int A = in_sizes[6];
  const int G = out_size;

  char* p = (char*)d_ws;
  auto carve = [&](size_t bytes)->char*{ char* r = p; p += (bytes + 255) & ~(size_t)255; return r; };
  float*    EbufA   = (float*)carve((size_t)E * D * 4);   // hidden, then sw
  float*    EbufB   = (float*)carve((size_t)E * D * 4);   // ek
  float*    ping0   = (float*)carve((size_t)N * D * 4);
  float*    ping1   = (float*)carve((size_t)N * D * 4);
  float*    bq      = (float*)carve((size_t)N * D * 4);   // q, then h
  float*    bk      = (float*)carve((size_t)N * D * 4);   // k, then MLP temp
  float*    bv      = (float*)carve((size_t)N * D * 4);   // v, then readout gate
  float*    bufAtoms= (float*)carve((size_t)A * D * 4);
  float*    a1      = (float*)carve((size_t)A * D * 4);
  float*    a2      = (float*)carve((size_t)A * D * 4);
  float*    logitB  = (float*)carve((size_t)E * NH * 4);
  unsigned* mEnc    = (unsigned*)carve((size_t)N * NH * 4);
  float*    denom   = (float*)carve((size_t)N * NH * 4);
  float*    results = (float*)carve((size_t)A * 4);
  double*   sumG    = (double*)carve((size_t)G * 8);
  double*   sumsqG  = (double*)carve((size_t)G * 8);
  int*      cntG    = (int*)carve((size_t)G * 4);
  float*    meanG   = (float*)carve((size_t)G * 4);
  float*    rstdG   = (float*)carve((size_t)G * 4);
  float*    W2e     = (float*)carve((size_t)LAYERS * D * D * 4);
  float*    B2e     = (float*)carve((size_t)LAYERS * D * 4);

  const int* srcA = edge_index;
  const int* dstA = edge_index + E;

  auto ew_grid = [](long total){ long b = (total + 255) / 256; return (int)(b < 4096 ? b : 4096); };
  auto gemm_grid = [](int M){ long t = ((long)M + 63) / 64; return (int)(t < 1024 ? t : 1024); };

  // one-time per launch
  hipMemsetAsync(cntG, 0, (size_t)G * 4, stream);
  hipMemsetAsync(results, 0, (size_t)A * 4, stream);
  hipMemsetAsync(d_out, 0, (size_t)G * 4, stream);
  k_count<<<ew_grid(N), 256, 0, stream>>>(batch, cntG, N);
  k_w2e<<<LAYERS * D, D, 0, stream>>>(edgenn_w2, conv_we, W2e);
  k_b2e<<<LAYERS, D, 0, stream>>>(edgenn_b2, conv_we, B2e);

  auto readout = [&](int i, const float* hbuf){
    k_rbf_gate<<<ew_grid((long)N * D), 256, 0, stream>>>(hbuf, node_rbf, read_wrbf + (size_t)i * RBFD * D, bv, N);
    hipMemsetAsync(bufAtoms, 0, (size_t)A * D * 4, stream);
    k_scatter<<<ew_grid((long)N * D), 256, 0, stream>>>(bv, eidx0, bufAtoms, N);
    k_gemm<D,1,false,true,false><<<gemm_grid(A),256,0,stream>>>(bufAtoms, nullptr, read_w1 + (size_t)i*D*D, read_b1 + (size_t)i*D, nullptr, a1, A);
    k_gemm<D,1,false,true,false><<<gemm_grid(A),256,0,stream>>>(a1, nullptr, read_w2 + (size_t)i*D*D, read_b2 + (size_t)i*D, nullptr, a2, A);
    k_dot3<<<((A * 64 + 255) / 256), 256, 0, stream>>>(a2, read_w3 + (size_t)i * D, read_b3 + i, results, A);
  };

  readout(0, x);

  const float* cur = x;
  float* pp[2] = {ping0, ping1};
  for (int i = 0; i < LAYERS; i++){
    float* nxt = pp[i & 1];
    const size_t oDD = (size_t)i * D * D;
    // atoms_rep = segsum(cur, eidx0)
    hipMemsetAsync(bufAtoms, 0, (size_t)A * D * 4, stream);
    k_scatter<<<ew_grid((long)N * D), 256, 0, stream>>>(cur, eidx0, bufAtoms, N);
    // hidden = silu(atoms_rep[pair_idx] @ w1 + b1)
    k_gemm<D,1,true,true,false><<<gemm_grid(E),256,0,stream>>>(bufAtoms, pair_idx, edgenn_w1 + oDD, edgenn_b1 + (size_t)i*D, nullptr, EbufA, E);
    // ek = hidden @ (w2@we) + b2@we
    k_gemm<D,0,false,true,false><<<gemm_grid(E),256,0,stream>>>(EbufA, nullptr, W2e + oDD, B2e + (size_t)i*D, nullptr, EbufB, E);
    // q, k, v
    k_gemm<D,0,false,false,false><<<gemm_grid(N),256,0,stream>>>(cur, nullptr, conv_wq + oDD, nullptr, nullptr, bq, N);
    k_gemm<D,0,false,false,false><<<gemm_grid(N),256,0,stream>>>(cur, nullptr, conv_wk + oDD, nullptr, nullptr, bk, N);
    k_gemm<D,0,false,false,false><<<gemm_grid(N),256,0,stream>>>(cur, nullptr, conv_wv + oDD, nullptr, nullptr, bv, N);
    // attention softmax
    hipMemsetAsync(mEnc, 0, (size_t)N * NH * 4, stream);
    k_logit_max<<<ew_grid((long)E * NH), 256, 0, stream>>>(bq, bk, EbufB, srcA, dstA, logitB, mEnc, E);
    hipMemsetAsync(denom, 0, (size_t)N * NH * 4, stream);
    k_exp_sum<<<ew_grid((long)E * NH), 256, 0, stream>>>(logitB, mEnc, dstA, denom, E);
    // sw = edge_sbf @ wsbf + bsbf  (reuse EbufA)
    k_gemm<SBFD,0,false,true,false><<<gemm_grid(E),256,0,stream>>>(edge_sbf, nullptr, conv_wsbf + (size_t)i*SBFD*D, conv_bsbf + (size_t)i*D, nullptr, EbufA, E);
    // h = segsum((v[src]+ek)*alpha*sw) into bq
    hipMemsetAsync(bq, 0, (size_t)N * D * 4, stream);
    k_message<<<ew_grid((long)E * D), 256, 0, stream>>>(bv, EbufB, EbufA, logitB, denom, srcA, dstA, bq, E);
    // rbf gate (in place)
    k_rbf_gate<<<ew_grid((long)N * D), 256, 0, stream>>>(bq, node_rbf, conv_wrbf + (size_t)i*RBFD*D, bq, N);
    // graph norm
    hipMemsetAsync(sumG, 0, (size_t)G * 8, stream);
    hipMemsetAsync(sumsqG, 0, (size_t)G * 8, stream);
    k_norm_stats<<<4096, 256, 0, stream>>>(bq, batch, sumG, sumsqG, N);
    k_norm_final<<<1, G, 0, stream>>>(sumG, sumsqG, cntG, meanG, rstdG);
    k_norm_apply<<<ew_grid((long)N * D), 256, 0, stream>>>(bq, batch, meanG, rstdG, N);
    // bf residual block
    k_gemm<D,1,false,true,false><<<gemm_grid(N),256,0,stream>>>(bq, nullptr, bf_w + (size_t)i*2*D*D, bf_b + (size_t)i*2*D, nullptr, bk, N);
    k_gemm<D,1,false,true,true ><<<gemm_grid(N),256,0,stream>>>(bk, nullptr, bf_w + (size_t)i*2*D*D + D*D, bf_b + (size_t)i*2*D + D, bq, bq, N);
    // dense + res0
    k_gemm<D,1,false,true,true ><<<gemm_grid(N),256,0,stream>>>(bq, nullptr, dense_w + oDD, dense_b + (size_t)i*D, cur, nxt, N);
    // af residual blocks
    k_gemm<D,1,false,true,false><<<gemm_grid(N),256,0,stream>>>(nxt, nullptr, af_w + (size_t)i*4*D*D,         af_b + (size_t)i*4*D,       nullptr, bk, N);
    k_gemm<D,1,false,true,true ><<<gemm_grid(N),256,0,stream>>>(bk, nullptr, af_w + (size_t)i*4*D*D + D*D,   af_b + (size_t)i*4*D + D,   nxt, nxt, N);
    k_gemm<D,1,false,true,false><<<gemm_grid(N),256,0,stream>>>(nxt, nullptr, af_w + (size_t)i*4*D*D + 2*D*D, af_b + (size_t)i*4*D + 2*D, nullptr, bk, N);
    k_gemm<D,1,false,true,true ><<<gemm_grid(N),256,0,stream>>>(bk, nullptr, af_w + (size_t)i*4*D*D + 3*D*D, af_b + (size_t)i*4*D + 3*D, nxt, nxt, N);
    // readout
    readout(i + 1, nxt);
    cur = nxt;
  }
  k_final<<<(A + 255) / 256, 256, 0, stream>>>(results, atom_batch, (float*)d_out, A);
}

// Round 3
// 3461.518 us; speedup vs baseline: 2.0723x; 1.1407x over previous
//
#include <hip/hip_runtime.h>
#include <math.h>

#define D    128
#define NH   8
#define CPH  16
#define RBFD 16
#define SBFD 112
#define LAYERS 3

typedef __attribute__((ext_vector_type(8))) short bf16x8;
typedef __attribute__((ext_vector_type(4))) float f32x4;

__device__ __forceinline__ float siluf(float x){ return x / (1.0f + __expf(-x)); }

__device__ __forceinline__ short f2bf(float f){
  union { float f; unsigned u; } v; v.f = f;
  unsigned r = v.u + 0x7FFFu + ((v.u >> 16) & 1u);   // RNE
  return (short)(r >> 16);
}

// ---------- MFMA GEMM: Y[M,128] = epilogue(X[gather?][.,DIN] @ W[DIN,128]) ----------
template<int DIN, int ACT, bool GATHER, bool HASB, bool HASRES>
__global__ __launch_bounds__(256, 2) void k_gemm(
    const float* __restrict__ X, const int* __restrict__ gidx,
    const float* __restrict__ W, const float* __restrict__ bias,
    const float* res, float* __restrict__ Y, int M)
{
  __shared__ short Wt[128 * 128];          // transposed bf16 weights: Wt[col][k]
  if (DIN < 128){
    for (int i = threadIdx.x; i < 128 * 128; i += 256) Wt[i] = 0;
    __syncthreads();
  }
  for (int i = threadIdx.x; i < DIN * 128; i += 256){
    int k = i >> 7, c = i & 127;
    Wt[c * 128 + k] = f2bf(W[i]);
  }
  __syncthreads();

  const int lane = threadIdx.x & 63;
  const int wave = threadIdx.x >> 6;
  const int col0 = lane & 15;
  const int kg   = lane >> 4;

  bf16x8 Bf[8][4];
  #pragma unroll
  for (int ct = 0; ct < 8; ct++)
    #pragma unroll
    for (int s = 0; s < 4; s++)
      Bf[ct][s] = *(const bf16x8*)&Wt[(ct * 16 + col0) * 128 + s * 32 + kg * 8];

  float bs[8];
  if (HASB){
    #pragma unroll
    for (int ct = 0; ct < 8; ct++) bs[ct] = bias[ct * 16 + col0];
  }

  const long tiles = ((long)M + 63) >> 6;
  for (long t = blockIdx.x; t < tiles; t += gridDim.x){
    const long rbase = t * 64 + wave * 16;
    const long arow  = rbase + col0;
    long srow = 0;
    if (arow < M) srow = GATHER ? (long)gidx[arow] : arow;
    const float* Xp = X + srow * DIN;

    bf16x8 Af[4];
    #pragma unroll
    for (int s = 0; s < 4; s++){
      const int kb = s * 32 + kg * 8;
      bf16x8 a;
      if (DIN == 128 || kb + 8 <= DIN){
        float4 lo = *(const float4*)(Xp + kb);
        float4 hi = *(const float4*)(Xp + kb + 4);
        a[0]=f2bf(lo.x); a[1]=f2bf(lo.y); a[2]=f2bf(lo.z); a[3]=f2bf(lo.w);
        a[4]=f2bf(hi.x); a[5]=f2bf(hi.y); a[6]=f2bf(hi.z); a[7]=f2bf(hi.w);
      } else {
        #pragma unroll
        for (int j = 0; j < 8; j++) a[j] = 0;
      }
      Af[s] = a;
    }

    f32x4 acc[8];
    #pragma unroll
    for (int ct = 0; ct < 8; ct++){ acc[ct][0]=0.f; acc[ct][1]=0.f; acc[ct][2]=0.f; acc[ct][3]=0.f; }
    #pragma unroll
    for (int ct = 0; ct < 8; ct++)
      #pragma unroll
      for (int s = 0; s < 4; s++)
        acc[ct] = __builtin_amdgcn_mfma_f32_16x16x32_bf16(Af[s], Bf[ct][s], acc[ct], 0, 0, 0);

    #pragma unroll
    for (int ct = 0; ct < 8; ct++){
      const int c = ct * 16 + col0;
      #pragma unroll
      for (int r = 0; r < 4; r++){
        const long orow = rbase + kg * 4 + r;
        if (orow < M){
          float v = acc[ct][r];
          if (HASB) v += bs[ct];
          if (ACT)  v = siluf(v);
          if (HASRES) v += res[orow * D + c];
          Y[orow * D + c] = v;
        }
      }
    }
  }
}

// ---------- fused edgenn: ek = silu(X[gidx]@W1+b1) @ W2 + b2 ----------
// intermediate kept in LDS (bf16, XOR-swizzled 16B granules), 2 blocks/CU.
__global__ __launch_bounds__(256, 2) void k_gemm2(
    const float* __restrict__ X, const int* __restrict__ gidx,
    const float* __restrict__ W1, const float* __restrict__ b1,
    const float* __restrict__ W2, const float* __restrict__ b2,
    float* __restrict__ Y, int M)
{
  __shared__ short W1t[128 * 128];
  __shared__ short W2t[128 * 128];
  __shared__ short Ts[64 * 128];
  for (int i = threadIdx.x; i < 128 * 128; i += 256){
    int k = i >> 7, c = i & 127;
    W1t[c * 128 + k] = f2bf(W1[i]);
    W2t[c * 128 + k] = f2bf(W2[i]);
  }
  __syncthreads();

  const int lane = threadIdx.x & 63;
  const int wave = threadIdx.x >> 6;
  const int col0 = lane & 15;
  const int kg   = lane >> 4;

  bf16x8 B1f[8][4];
  #pragma unroll
  for (int ct = 0; ct < 8; ct++)
    #pragma unroll
    for (int s = 0; s < 4; s++)
      B1f[ct][s] = *(const bf16x8*)&W1t[(ct * 16 + col0) * 128 + s * 32 + kg * 8];

  float bs1[8], bs2[8];
  #pragma unroll
  for (int ct = 0; ct < 8; ct++){ bs1[ct] = b1[ct * 16 + col0]; bs2[ct] = b2[ct * 16 + col0]; }

  const long tiles = ((long)M + 63) >> 6;
  for (long t = blockIdx.x; t < tiles; t += gridDim.x){
    const long rbase = t * 64 + wave * 16;
    const long arow  = rbase + col0;
    long srow = 0;
    if (arow < M) srow = (long)gidx[arow];
    const float* Xp = X + srow * D;

    bf16x8 Af[4];
    #pragma unroll
    for (int s = 0; s < 4; s++){
      const int kb = s * 32 + kg * 8;
      float4 lo = *(const float4*)(Xp + kb);
      float4 hi = *(const float4*)(Xp + kb + 4);
      bf16x8 a;
      a[0]=f2bf(lo.x); a[1]=f2bf(lo.y); a[2]=f2bf(lo.z); a[3]=f2bf(lo.w);
      a[4]=f2bf(hi.x); a[5]=f2bf(hi.y); a[6]=f2bf(hi.z); a[7]=f2bf(hi.w);
      Af[s] = a;
    }

    f32x4 acc[8];
    #pragma unroll
    for (int ct = 0; ct < 8; ct++){ acc[ct][0]=0.f; acc[ct][1]=0.f; acc[ct][2]=0.f; acc[ct][3]=0.f; }
    #pragma unroll
    for (int ct = 0; ct < 8; ct++)
      #pragma unroll
      for (int s = 0; s < 4; s++)
        acc[ct] = __builtin_amdgcn_mfma_f32_16x16x32_bf16(Af[s], B1f[ct][s], acc[ct], 0, 0, 0);

    // T = silu(acc + b1) -> LDS (swizzled)
    #pragma unroll
    for (int ct = 0; ct < 8; ct++){
      const int c = ct * 16 + col0;
      #pragma unroll
      for (int r = 0; r < 4; r++){
        const int row = wave * 16 + kg * 4 + r;
        const int gg = (c >> 3) ^ (row & 7);
        Ts[row * 128 + gg * 8 + (c & 7)] = f2bf(siluf(acc[ct][r] + bs1[ct]));
      }
    }
    __syncthreads();

    const int row2 = wave * 16 + col0;
    bf16x8 A2f[4];
    #pragma unroll
    for (int s = 0; s < 4; s++){
      const int chunk = (s * 4 + kg) ^ (row2 & 7);
      A2f[s] = *(const bf16x8*)&Ts[row2 * 128 + chunk * 8];
    }
    __syncthreads();

    #pragma unroll
    for (int ct = 0; ct < 8; ct++){ acc[ct][0]=0.f; acc[ct][1]=0.f; acc[ct][2]=0.f; acc[ct][3]=0.f; }
    #pragma unroll
    for (int ct = 0; ct < 8; ct++){
      bf16x8 B2v[4];
      #pragma unroll
      for (int s = 0; s < 4; s++)
        B2v[s] = *(const bf16x8*)&W2t[(ct * 16 + col0) * 128 + s * 32 + kg * 8];
      #pragma unroll
      for (int s = 0; s < 4; s++)
        acc[ct] = __builtin_amdgcn_mfma_f32_16x16x32_bf16(A2f[s], B2v[s], acc[ct], 0, 0, 0);
    }

    #pragma unroll
    for (int ct = 0; ct < 8; ct++){
      const int c = ct * 16 + col0;
      #pragma unroll
      for (int r = 0; r < 4; r++){
        const long orow = rbase + kg * 4 + r;
        if (orow < M) Y[orow * D + c] = acc[ct][r] + bs2[ct];
      }
    }
  }
}

// ---------- CSR build ----------
__global__ void k_hist(const int* __restrict__ idx, int* __restrict__ cnt, int M)
{
  for (long i = (long)blockIdx.x * 256 + threadIdx.x; i < M; i += (long)gridDim.x * 256)
    atomicAdd(&cnt[idx[i]], 1);
}

__global__ void k_scan(const int* __restrict__ cnt, int* __restrict__ rowptr, int M)
{
  __shared__ int buf[1024];
  const int tid = threadIdx.x;
  const int PT = 16;
  int carry = 0;
  for (int base = 0; base < M; base += 1024 * PT){
    int loc[PT]; int s = 0;
    #pragma unroll
    for (int j = 0; j < PT; j++){
      int i = base + tid * PT + j;
      loc[j] = (i < M) ? cnt[i] : 0;
      s += loc[j];
    }
    buf[tid] = s; __syncthreads();
    for (int off = 1; off < 1024; off <<= 1){
      int t = (tid >= off) ? buf[tid - off] : 0;
      __syncthreads();
      buf[tid] += t;
      __syncthreads();
    }
    int run = buf[tid] - s + carry;
    carry += buf[1023];
    __syncthreads();
    #pragma unroll
    for (int j = 0; j < PT; j++){
      int i = base + tid * PT + j;
      if (i < M) rowptr[i] = run;
      run += loc[j];
    }
  }
  if (tid == 0) rowptr[M] = carry;
}

__global__ void k_fill(const int* __restrict__ idx, const int* __restrict__ rowptr,
                       int* __restrict__ cursor, int* __restrict__ ids, int M)
{
  for (long i = (long)blockIdx.x * 256 + threadIdx.x; i < M; i += (long)gridDim.x * 256){
    int sgm = idx[i];
    int pos = atomicAdd(&cursor[sgm], 1);
    ids[rowptr[sgm] + pos] = (int)i;
  }
}

// ---------- CSR gather-sum (atoms_rep) ----------
__global__ __launch_bounds__(256) void k_gather_sum(
    const float* __restrict__ X, const int* __restrict__ rowptr,
    const int* __restrict__ ids, float* __restrict__ Yat, int A_)
{
  const int lane = threadIdx.x & 63;
  const int wv   = threadIdx.x >> 6;
  for (long a = (long)blockIdx.x * 4 + wv; a < A_; a += (long)gridDim.x * 4){
    int beg = rowptr[a], end = rowptr[a + 1];
    float a0 = 0.f, a1 = 0.f;
    for (int i = beg; i < end; i++){
      const float* xp = X + (long)ids[i] * D;
      a0 += xp[lane]; a1 += xp[lane + 64];
    }
    Yat[a * D + lane] = a0; Yat[a * D + lane + 64] = a1;
  }
}

// ---------- CSR gather with rbf gate (readout scatter) ----------
__global__ __launch_bounds__(256) void k_gather_gate_sum(
    const float* __restrict__ X, const float* __restrict__ rbf,
    const float* __restrict__ Wr, const int* __restrict__ rowptr,
    const int* __restrict__ ids, float* __restrict__ Yat, int A_)
{
  __shared__ float Wrs[RBFD * D];
  for (int i = threadIdx.x; i < RBFD * D; i += 256) Wrs[i] = Wr[i];
  __syncthreads();
  const int lane = threadIdx.x & 63;
  const int wv   = threadIdx.x >> 6;
  for (long a = (long)blockIdx.x * 4 + wv; a < A_; a += (long)gridDim.x * 4){
    int beg = rowptr[a], end = rowptr[a + 1];
    float a0 = 0.f, a1 = 0.f;
    for (int i = beg; i < end; i++){
      long n = ids[i];
      const float* xp = X + n * D;
      const float* rb = rbf + n * RBFD;
      float g0 = 0.f, g1 = 0.f;
      #pragma unroll
      for (int r = 0; r < RBFD; r++){
        float rv = rb[r];
        g0 += rv * Wrs[r * D + lane];
        g1 += rv * Wrs[r * D + lane + 64];
      }
      a0 += xp[lane] * g0; a1 += xp[lane + 64] * g1;
    }
    Yat[a * D + lane] = a0; Yat[a * D + lane + 64] = a1;
  }
}

// ---------- fused attention: online softmax + message + rbf gate + norm stats ----------
// one wave per dst node; writes h over q in place (each wave reads only its own q row).
__global__ __launch_bounds__(256) void k_attn(
    float* __restrict__ q, const float* __restrict__ k, const float* __restrict__ v,
    const float* __restrict__ ek, const float* __restrict__ sw,
    const int* __restrict__ rowptr, const int* __restrict__ eids,
    const int* __restrict__ srcA, const float* __restrict__ rbf,
    const float* __restrict__ Wr, const int* __restrict__ batch,
    double* __restrict__ sums, double* __restrict__ sumsq, int Nn)
{
  __shared__ float Wrs[RBFD * D];
  for (int i = threadIdx.x; i < RBFD * D; i += 256) Wrs[i] = Wr[i];
  __syncthreads();
  const int lane = threadIdx.x & 63;
  const int wv   = threadIdx.x >> 6;
  for (long d = (long)blockIdx.x * 4 + wv; d < Nn; d += (long)gridDim.x * 4){
    const int beg = rowptr[d], end = rowptr[d + 1];
    const float q0 = q[d * D + lane], q1 = q[d * D + lane + 64];
    float m0 = -1e30f, m1 = -1e30f, l0 = 0.f, l1 = 0.f, a0 = 0.f, a1 = 0.f;
    for (int i = beg; i < end; i++){
      const long e = eids[i];
      const long s = srcA[e];
      const float* kp = k  + s * D;
      const float* vp = v  + s * D;
      const float* ep = ek + e * D;
      const float* sp = sw + e * D;
      float e0 = ep[lane], e1 = ep[lane + 64];
      float t0 = q0 * (kp[lane] + e0), t1 = q1 * (kp[lane + 64] + e1);
      #pragma unroll
      for (int off = 1; off < 16; off <<= 1){
        t0 += __shfl_xor(t0, off, 64);
        t1 += __shfl_xor(t1, off, 64);
      }
      t0 *= 0.25f; t1 *= 0.25f;
      float u0 = (vp[lane] + e0) * sp[lane];
      float u1 = (vp[lane + 64] + e1) * sp[lane + 64];
      float nm0 = fmaxf(m0, t0), nm1 = fmaxf(m1, t1);
      float sc0 = __expf(m0 - nm0), sc1 = __expf(m1 - nm1);
      float w0 = __expf(t0 - nm0), w1 = __expf(t1 - nm1);
      l0 = l0 * sc0 + w0;  a0 = a0 * sc0 + w0 * u0;  m0 = nm0;
      l1 = l1 * sc1 + w1;  a1 = a1 * sc1 + w1 * u1;  m1 = nm1;
    }
    a0 /= (l0 + 1e-16f); a1 /= (l1 + 1e-16f);
    // rbf gate
    const float* rb = rbf + d * RBFD;
    float g0 = 0.f, g1 = 0.f;
    #pragma unroll
    for (int r = 0; r < RBFD; r++){
      float rv = rb[r];
      g0 += rv * Wrs[r * D + lane];
      g1 += rv * Wrs[r * D + lane + 64];
    }
    a0 *= g0; a1 *= g1;
    q[d * D + lane] = a0; q[d * D + lane + 64] = a1;
    // graph-norm stats
    float ss = a0 + a1, qq = a0 * a0 + a1 * a1;
    #pragma unroll
    for (int off = 1; off < 64; off <<= 1){
      ss += __shfl_xor(ss, off, 64);
      qq += __shfl_xor(qq, off, 64);
    }
    if (lane == 0){
      int g = batch[d];
      atomicAdd(&sums[g], (double)ss);
      atomicAdd(&sumsq[g], (double)qq);
    }
  }
}

// ---------- graph norm ----------
__global__ void k_count(const int* __restrict__ batch, int* __restrict__ cnt, int M)
{
  for (long i = (long)blockIdx.x * 256 + threadIdx.x; i < M; i += (long)gridDim.x * 256)
    atomicAdd(&cnt[batch[i]], 1);
}

__global__ void k_norm_final(const double* __restrict__ sums, const double* __restrict__ sumsq,
                             const int* __restrict__ cnt, float* __restrict__ meanG,
                             float* __restrict__ rstdG)
{
  int g = threadIdx.x;
  double c = (double)cnt[g] * (double)D;
  double mean = sums[g] / c;
  double var = sumsq[g] / c - mean * mean;
  meanG[g] = (float)mean;
  rstdG[g] = (float)(1.0 / sqrt(var + 1e-8));
}

__global__ void k_norm_apply(float* __restrict__ Hio, const int* __restrict__ batch,
                             const float* __restrict__ meanG, const float* __restrict__ rstdG, int M)
{
  long total = (long)M * D;
  for (long i = (long)blockIdx.x * 256 + threadIdx.x; i < total; i += (long)gridDim.x * 256){
    long row = i >> 7;
    int g = batch[row];
    Hio[i] = (Hio[i] - meanG[g]) * rstdG[g];
  }
}

// ---------- readout tail ----------
__global__ void k_dot3(const float* __restrict__ A2, const float* __restrict__ w3,
                       const float* __restrict__ b3, float* __restrict__ results, int M)
{
  int lane = threadIdx.x & 63;
  long wave = ((long)blockIdx.x * blockDim.x + threadIdx.x) >> 6;
  long nw = ((long)gridDim.x * blockDim.x) >> 6;
  for (long row = wave; row < M; row += nw){
    float a = A2[row * D + lane] * w3[lane] + A2[row * D + lane + 64] * w3[lane + 64];
    for (int off = 32; off > 0; off >>= 1) a += __shfl_down(a, off, 64);
    if (lane == 0) results[row] += a + b3[0];
  }
}

__global__ void k_final(const float* __restrict__ results, const int* __restrict__ ab,
                        float* __restrict__ out, int A_)
{
  int i = blockIdx.x * 256 + threadIdx.x;
  if (i < A_) atomicAdd(&out[ab[i]], results[i] / 3.0f);
}

// ---------- fold w2@we, b2@we ----------
__global__ void k_w2e(const float* __restrict__ w2, const float* __restrict__ we,
                      float* __restrict__ W2e)
{
  int i = blockIdx.x >> 7;
  int r = blockIdx.x & 127;
  int c = threadIdx.x;
  const float* w2p = w2 + (size_t)i * D * D + (size_t)r * D;
  const float* wep = we + (size_t)i * D * D;
  float acc = 0.f;
  for (int j = 0; j < D; j++) acc += w2p[j] * wep[j * D + c];
  W2e[(size_t)i * D * D + (size_t)r * D + c] = acc;
}

__global__ void k_b2e(const float* __restrict__ b2, const float* __restrict__ we,
                      float* __restrict__ B2e)
{
  int i = blockIdx.x; int c = threadIdx.x;
  float acc = 0.f;
  for (int j = 0; j < D; j++) acc += b2[(size_t)i * D + j] * we[(size_t)i * D * D + j * D + c];
  B2e[(size_t)i * D + c] = acc;
}

extern "C" void kernel_launch(void* const* d_in, const int* in_sizes, int n_in,
                              void* d_out, int out_size, void* d_ws, size_t ws_size,
                              hipStream_t stream)
{
  const float* x          = (const float*)d_in[0];
  const float* node_rbf   = (const float*)d_in[1];
  const float* edge_sbf   = (const float*)d_in[2];
  const int*   edge_index = (const int*)d_in[3];
  const int*   pair_idx   = (const int*)d_in[4];
  const int*   eidx0      = (const int*)d_in[5];
  const int*   atom_batch = (const int*)d_in[6];
  const int*   batch      = (const int*)d_in[7];
  const float* edgenn_w1  = (const float*)d_in[8];
  const float* edgenn_b1  = (const float*)d_in[9];
  const float* edgenn_w2  = (const float*)d_in[10];
  const float* edgenn_b2  = (const float*)d_in[11];
  const float* conv_wq    = (const float*)d_in[12];
  const float* conv_wk    = (const float*)d_in[13];
  const float* conv_wv    = (const float*)d_in[14];
  const float* conv_we    = (const float*)d_in[15];
  const float* conv_wsbf  = (const float*)d_in[16];
  const float* conv_bsbf  = (const float*)d_in[17];
  const float* conv_wrbf  = (const float*)d_in[18];
  const float* dense_w    = (const float*)d_in[19];
  const float* dense_b    = (const float*)d_in[20];
  const float* bf_w       = (const float*)d_in[21];
  const float* bf_b       = (const float*)d_in[22];
  const float* af_w       = (const float*)d_in[23];
  const float* af_b       = (const float*)d_in[24];
  const float* read_wrbf  = (const float*)d_in[25];
  const float* read_w1    = (const float*)d_in[26];
  const float* read_b1    = (const float*)d_in[27];
  const float* read_w2    = (const float*)d_in[28];
  const float* read_b2    = (const float*)d_in[29];
  const float* read_w3    = (const float*)d_in[30];
  const float* read_b3    = (const float*)d_in[31];

  const int N = in_sizes[0] / D;
  const int E = in_sizes[4];
  const int A = in_sizes[6];
  const int G = out_size;

  char* p = (char*)d_ws;
  auto carve = [&](size_t bytes)->char*{ char* r = p; p += (bytes + 255) & ~(size_t)255; return r; };
  float*    EbufA   = (float*)carve((size_t)E * D * 4);   // sw
  float*    EbufB   = (float*)carve((size_t)E * D * 4);   // ek
  float*    ping0   = (float*)carve((size_t)N * D * 4);
  float*    ping1   = (float*)carve((size_t)N * D * 4);
  float*    bq      = (float*)carve((size_t)N * D * 4);   // q -> h
  float*    bk      = (float*)carve((size_t)N * D * 4);
  float*    bv      = (float*)carve((size_t)N * D * 4);
  float*    bufAtoms= (float*)carve((size_t)A * D * 4);
  float*    a1      = (float*)carve((size_t)A * D * 4);
  float*    a2      = (float*)carve((size_t)A * D * 4);
  float*    results = (float*)carve((size_t)A * 4);
  double*   sumG    = (double*)carve((size_t)G * 8);
  double*   sumsqG  = (double*)carve((size_t)G * 8);
  int*      cntG    = (int*)carve((size_t)G * 4);
  float*    meanG   = (float*)carve((size_t)G * 4);
  float*    rstdG   = (float*)carve((size_t)G * 4);
  float*    W2e     = (float*)carve((size_t)LAYERS * D * D * 4);
  float*    B2e     = (float*)carve((size_t)LAYERS * D * 4);
  int*      rowptrD = (int*)carve((size_t)(N + 1) * 4);
  int*      eidsD   = (int*)carve((size_t)E * 4);
  int*      cntD    = (int*)carve((size_t)N * 4);
  int*      rowptrA = (int*)carve((size_t)(A + 1) * 4);
  int*      idsA    = (int*)carve((size_t)N * 4);
  int*      cntA    = (int*)carve((size_t)A * 4);

  const int* srcA = edge_index;
  const int* dstA = edge_index + E;

  auto ew_grid = [](long total){ long b = (total + 255) / 256; return (int)(b < 4096 ? b : 4096); };
  auto gemm_grid = [](int M){ long t = ((long)M + 63) / 64; return (int)(t < 1024 ? t : 1024); };
  const int gridAttn = (N + 3) / 4;
  const int gridAtom = (A + 3) / 4;

  // ---- one-time setup ----
  hipMemsetAsync(cntG, 0, (size_t)G * 4, stream);
  hipMemsetAsync(results, 0, (size_t)A * 4, stream);
  hipMemsetAsync(d_out, 0, (size_t)G * 4, stream);
  k_count<<<ew_grid(N), 256, 0, stream>>>(batch, cntG, N);
  k_w2e<<<LAYERS * D, D, 0, stream>>>(edgenn_w2, conv_we, W2e);
  k_b2e<<<LAYERS, D, 0, stream>>>(edgenn_b2, conv_we, B2e);
  // CSR by dst (edges)
  hipMemsetAsync(cntD, 0, (size_t)N * 4, stream);
  k_hist<<<ew_grid(E), 256, 0, stream>>>(dstA, cntD, E);
  k_scan<<<1, 1024, 0, stream>>>(cntD, rowptrD, N);
  hipMemsetAsync(cntD, 0, (size_t)N * 4, stream);
  k_fill<<<ew_grid(E), 256, 0, stream>>>(dstA, rowptrD, cntD, eidsD, E);
  // CSR by atom (nodes)
  hipMemsetAsync(cntA, 0, (size_t)A * 4, stream);
  k_hist<<<ew_grid(N), 256, 0, stream>>>(eidx0, cntA, N);
  k_scan<<<1, 1024, 0, stream>>>(cntA, rowptrA, A);
  hipMemsetAsync(cntA, 0, (size_t)A * 4, stream);
  k_fill<<<ew_grid(N), 256, 0, stream>>>(eidx0, rowptrA, cntA, idsA, N);

  auto readout = [&](int i, const float* hbuf){
    k_gather_gate_sum<<<gridAtom, 256, 0, stream>>>(hbuf, node_rbf, read_wrbf + (size_t)i * RBFD * D,
                                                    rowptrA, idsA, bufAtoms, A);
    k_gemm<D,1,false,true,false><<<gemm_grid(A),256,0,stream>>>(bufAtoms, nullptr, read_w1 + (size_t)i*D*D, read_b1 + (size_t)i*D, nullptr, a1, A);
    k_gemm<D,1,false,true,false><<<gemm_grid(A),256,0,stream>>>(a1, nullptr, read_w2 + (size_t)i*D*D, read_b2 + (size_t)i*D, nullptr, a2, A);
    k_dot3<<<((A * 64 + 255) / 256), 256, 0, stream>>>(a2, read_w3 + (size_t)i * D, read_b3 + i, results, A);
  };

  readout(0, x);

  const float* cur = x;
  float* pp[2] = {ping0, ping1};
  for (int i = 0; i < LAYERS; i++){
    float* nxt = pp[i & 1];
    const size_t oDD = (size_t)i * D * D;
    // atoms_rep = segsum(cur, eidx0)  (CSR gather)
    k_gather_sum<<<gridAtom, 256, 0, stream>>>(cur, rowptrA, idsA, bufAtoms, A);
    // ek = silu(atoms_rep[pair_idx]@w1+b1) @ (w2@we) + b2@we   (fused)
    k_gemm2<<<gemm_grid(E),256,0,stream>>>(bufAtoms, pair_idx, edgenn_w1 + oDD, edgenn_b1 + (size_t)i*D,
                                           W2e + oDD, B2e + (size_t)i*D, EbufB, E);
    // q, k, v
    k_gemm<D,0,false,false,false><<<gemm_grid(N),256,0,stream>>>(cur, nullptr, conv_wq + oDD, nullptr, nullptr, bq, N);
    k_gemm<D,0,false,false,false><<<gemm_grid(N),256,0,stream>>>(cur, nullptr, conv_wk + oDD, nullptr, nullptr, bk, N);
    k_gemm<D,0,false,false,false><<<gemm_grid(N),256,0,stream>>>(cur, nullptr, conv_wv + oDD, nullptr, nullptr, bv, N);
    // sw = edge_sbf @ wsbf + bsbf
    k_gemm<SBFD,0,false,true,false><<<gemm_grid(E),256,0,stream>>>(edge_sbf, nullptr, conv_wsbf + (size_t)i*SBFD*D, conv_bsbf + (size_t)i*D, nullptr, EbufA, E);
    // fused attention + rbf gate + stats; h written over bq
    hipMemsetAsync(sumG, 0, (size_t)G * 8, stream);
    hipMemsetAsync(sumsqG, 0, (size_t)G * 8, stream);
    k_attn<<<gridAttn, 256, 0, stream>>>(bq, bk, bv, EbufB, EbufA, rowptrD, eidsD, srcA,
                                         node_rbf, conv_wrbf + (size_t)i*RBFD*D, batch,
                                         sumG, sumsqG, N);
    k_norm_final<<<1, G, 0, stream>>>(sumG, sumsqG, cntG, meanG, rstdG);
    k_norm_apply<<<ew_grid((long)N * D), 256, 0, stream>>>(bq, batch, meanG, rstdG, N);
    // bf residual block
    k_gemm<D,1,false,true,false><<<gemm_grid(N),256,0,stream>>>(bq, nullptr, bf_w + (size_t)i*2*D*D, bf_b + (size_t)i*2*D, nullptr, bk, N);
    k_gemm<D,1,false,true,true ><<<gemm_grid(N),256,0,stream>>>(bk, nullptr, bf_w + (size_t)i*2*D*D + D*D, bf_b + (size_t)i*2*D + D, bq, bq, N);
    // dense + res0
    k_gemm<D,1,false,true,true ><<<gemm_grid(N),256,0,stream>>>(bq, nullptr, dense_w + oDD, dense_b + (size_t)i*D, cur, nxt, N);
    // af residual blocks
    k_gemm<D,1,false,true,false><<<gemm_grid(N),256,0,stream>>>(nxt, nullptr, af_w + (size_t)i*4*D*D,         af_b + (size_t)i*4*D,       nullptr, bk, N);
    k_gemm<D,1,false,true,true ><<<gemm_grid(N),256,0,stream>>>(bk, nullptr, af_w + (size_t)i*4*D*D + D*D,   af_b + (size_t)i*4*D + D,   nxt, nxt, N);
    k_gemm<D,1,false,true,false><<<gemm_grid(N),256,0,stream>>>(nxt, nullptr, af_w + (size_t)i*4*D*D + 2*D*D, af_b + (size_t)i*4*D + 2*D, nullptr, bk, N);
    k_gemm<D,1,false,true,true ><<<gemm_grid(N),256,0,stream>>>(bk, nullptr, af_w + (size_t)i*4*D*D + 3*D*D, af_b + (size_t)i*4*D + 3*D, nxt, nxt, N);
    // readout
    readout(i + 1, nxt);
    cur = nxt;
  }
  k_final<<<(A + 255) / 256, 256, 0, stream>>>(results, atom_batch, (float*)d_out, A);
}

// Round 4
// 3254.816 us; speedup vs baseline: 2.2039x; 1.0635x over previous
//
#include <hip/hip_runtime.h>
#include <math.h>

#define D    128
#define NH   8
#define CPH  16
#define RBFD 16
#define SBFD 112
#define LAYERS 3

typedef __attribute__((ext_vector_type(8))) short bf16x8;
typedef __attribute__((ext_vector_type(4))) float f32x4;

__device__ __forceinline__ float siluf(float x){ return x / (1.0f + __expf(-x)); }

__device__ __forceinline__ short f2bf(float f){
  union { float f; unsigned u; } v; v.f = f;
  unsigned r = v.u + 0x7FFFu + ((v.u >> 16) & 1u);   // RNE
  return (short)(r >> 16);
}

// ---------- MFMA GEMM: Y[M,128] = epilogue(X[gather?][.,DIN] @ W[DIN,128]) ----------
template<int DIN, int ACT, bool GATHER, bool HASB, bool HASRES, bool PERM>
__global__ __launch_bounds__(256, 2) void k_gemm(
    const float* __restrict__ X, const int* __restrict__ gidx,
    const float* __restrict__ W, const float* __restrict__ bias,
    const float* res, float* __restrict__ Y, const int* __restrict__ operm, int M)
{
  __shared__ short Wt[128 * 128];          // transposed bf16 weights: Wt[col][k]
  if (DIN < 128){
    for (int i = threadIdx.x; i < 128 * 128; i += 256) Wt[i] = 0;
    __syncthreads();
  }
  for (int i = threadIdx.x; i < DIN * 128; i += 256){
    int k = i >> 7, c = i & 127;
    Wt[c * 128 + k] = f2bf(W[i]);
  }
  __syncthreads();

  const int lane = threadIdx.x & 63;
  const int wave = threadIdx.x >> 6;
  const int col0 = lane & 15;
  const int kg   = lane >> 4;

  bf16x8 Bf[8][4];
  #pragma unroll
  for (int ct = 0; ct < 8; ct++)
    #pragma unroll
    for (int s = 0; s < 4; s++)
      Bf[ct][s] = *(const bf16x8*)&Wt[(ct * 16 + col0) * 128 + s * 32 + kg * 8];

  float bs[8];
  if (HASB){
    #pragma unroll
    for (int ct = 0; ct < 8; ct++) bs[ct] = bias[ct * 16 + col0];
  }

  const long tiles = ((long)M + 63) >> 6;
  for (long t = blockIdx.x; t < tiles; t += gridDim.x){
    const long rbase = t * 64 + wave * 16;
    const long arow  = rbase + col0;
    long srow = 0;
    if (arow < M) srow = GATHER ? (long)gidx[arow] : arow;
    const float* Xp = X + srow * DIN;

    bf16x8 Af[4];
    #pragma unroll
    for (int s = 0; s < 4; s++){
      const int kb = s * 32 + kg * 8;
      bf16x8 a;
      if (DIN == 128 || kb + 8 <= DIN){
        float4 lo = *(const float4*)(Xp + kb);
        float4 hi = *(const float4*)(Xp + kb + 4);
        a[0]=f2bf(lo.x); a[1]=f2bf(lo.y); a[2]=f2bf(lo.z); a[3]=f2bf(lo.w);
        a[4]=f2bf(hi.x); a[5]=f2bf(hi.y); a[6]=f2bf(hi.z); a[7]=f2bf(hi.w);
      } else {
        #pragma unroll
        for (int j = 0; j < 8; j++) a[j] = 0;
      }
      Af[s] = a;
    }

    f32x4 acc[8];
    #pragma unroll
    for (int ct = 0; ct < 8; ct++){ acc[ct][0]=0.f; acc[ct][1]=0.f; acc[ct][2]=0.f; acc[ct][3]=0.f; }
    #pragma unroll
    for (int ct = 0; ct < 8; ct++)
      #pragma unroll
      for (int s = 0; s < 4; s++)
        acc[ct] = __builtin_amdgcn_mfma_f32_16x16x32_bf16(Af[s], Bf[ct][s], acc[ct], 0, 0, 0);

    #pragma unroll
    for (int r = 0; r < 4; r++){
      const long orow = rbase + kg * 4 + r;
      if (orow >= M) continue;
      const long wrow = PERM ? (long)operm[orow] : orow;
      #pragma unroll
      for (int ct = 0; ct < 8; ct++){
        const int c = ct * 16 + col0;
        float v = acc[ct][r];
        if (HASB) v += bs[ct];
        if (ACT)  v = siluf(v);
        if (HASRES) v += res[orow * D + c];
        Y[wrow * D + c] = v;
      }
    }
  }
}

// ---------- fused edgenn: ek = silu(X[gidx]@W1+b1) @ W2 + b2, output permuted ----------
__global__ __launch_bounds__(256, 2) void k_gemm2(
    const float* __restrict__ X, const int* __restrict__ gidx,
    const float* __restrict__ W1, const float* __restrict__ b1,
    const float* __restrict__ W2, const float* __restrict__ b2,
    float* __restrict__ Y, const int* __restrict__ operm, int M)
{
  __shared__ short W1t[128 * 128];
  __shared__ short W2t[128 * 128];
  __shared__ short Ts[64 * 128];
  for (int i = threadIdx.x; i < 128 * 128; i += 256){
    int k = i >> 7, c = i & 127;
    W1t[c * 128 + k] = f2bf(W1[i]);
    W2t[c * 128 + k] = f2bf(W2[i]);
  }
  __syncthreads();

  const int lane = threadIdx.x & 63;
  const int wave = threadIdx.x >> 6;
  const int col0 = lane & 15;
  const int kg   = lane >> 4;

  bf16x8 B1f[8][4];
  #pragma unroll
  for (int ct = 0; ct < 8; ct++)
    #pragma unroll
    for (int s = 0; s < 4; s++)
      B1f[ct][s] = *(const bf16x8*)&W1t[(ct * 16 + col0) * 128 + s * 32 + kg * 8];

  float bs1[8], bs2[8];
  #pragma unroll
  for (int ct = 0; ct < 8; ct++){ bs1[ct] = b1[ct * 16 + col0]; bs2[ct] = b2[ct * 16 + col0]; }

  const long tiles = ((long)M + 63) >> 6;
  for (long t = blockIdx.x; t < tiles; t += gridDim.x){
    const long rbase = t * 64 + wave * 16;
    const long arow  = rbase + col0;
    long srow = 0;
    if (arow < M) srow = (long)gidx[arow];
    const float* Xp = X + srow * D;

    bf16x8 Af[4];
    #pragma unroll
    for (int s = 0; s < 4; s++){
      const int kb = s * 32 + kg * 8;
      float4 lo = *(const float4*)(Xp + kb);
      float4 hi = *(const float4*)(Xp + kb + 4);
      bf16x8 a;
      a[0]=f2bf(lo.x); a[1]=f2bf(lo.y); a[2]=f2bf(lo.z); a[3]=f2bf(lo.w);
      a[4]=f2bf(hi.x); a[5]=f2bf(hi.y); a[6]=f2bf(hi.z); a[7]=f2bf(hi.w);
      Af[s] = a;
    }

    f32x4 acc[8];
    #pragma unroll
    for (int ct = 0; ct < 8; ct++){ acc[ct][0]=0.f; acc[ct][1]=0.f; acc[ct][2]=0.f; acc[ct][3]=0.f; }
    #pragma unroll
    for (int ct = 0; ct < 8; ct++)
      #pragma unroll
      for (int s = 0; s < 4; s++)
        acc[ct] = __builtin_amdgcn_mfma_f32_16x16x32_bf16(Af[s], B1f[ct][s], acc[ct], 0, 0, 0);

    #pragma unroll
    for (int ct = 0; ct < 8; ct++){
      const int c = ct * 16 + col0;
      #pragma unroll
      for (int r = 0; r < 4; r++){
        const int row = wave * 16 + kg * 4 + r;
        const int gg = (c >> 3) ^ (row & 7);
        Ts[row * 128 + gg * 8 + (c & 7)] = f2bf(siluf(acc[ct][r] + bs1[ct]));
      }
    }
    __syncthreads();

    const int row2 = wave * 16 + col0;
    bf16x8 A2f[4];
    #pragma unroll
    for (int s = 0; s < 4; s++){
      const int chunk = (s * 4 + kg) ^ (row2 & 7);
      A2f[s] = *(const bf16x8*)&Ts[row2 * 128 + chunk * 8];
    }
    __syncthreads();

    #pragma unroll
    for (int ct = 0; ct < 8; ct++){ acc[ct][0]=0.f; acc[ct][1]=0.f; acc[ct][2]=0.f; acc[ct][3]=0.f; }
    #pragma unroll
    for (int ct = 0; ct < 8; ct++){
      bf16x8 B2v[4];
      #pragma unroll
      for (int s = 0; s < 4; s++)
        B2v[s] = *(const bf16x8*)&W2t[(ct * 16 + col0) * 128 + s * 32 + kg * 8];
      #pragma unroll
      for (int s = 0; s < 4; s++)
        acc[ct] = __builtin_amdgcn_mfma_f32_16x16x32_bf16(A2f[s], B2v[s], acc[ct], 0, 0, 0);
    }

    #pragma unroll
    for (int r = 0; r < 4; r++){
      const long orow = rbase + kg * 4 + r;
      if (orow >= M) continue;
      const long wrow = (long)operm[orow];
      #pragma unroll
      for (int ct = 0; ct < 8; ct++){
        const int c = ct * 16 + col0;
        Y[wrow * D + c] = acc[ct][r] + bs2[ct];
      }
    }
  }
}

// ---------- fused residual block: Y = norm?(X) + silu(silu(norm?(X)@W1+b1)@W2+b2) ----------
template<bool NORM>
__global__ __launch_bounds__(256, 2) void k_res2(
    const float* __restrict__ X,
    const float* __restrict__ W1, const float* __restrict__ b1,
    const float* __restrict__ W2, const float* __restrict__ b2,
    const int* __restrict__ batch, const float* __restrict__ meanG,
    const float* __restrict__ rstdG, float* __restrict__ Y, int M)
{
  __shared__ short W1t[128 * 128];
  __shared__ short W2t[128 * 128];
  __shared__ short Ts[64 * 128];
  for (int i = threadIdx.x; i < 128 * 128; i += 256){
    int k = i >> 7, c = i & 127;
    W1t[c * 128 + k] = f2bf(W1[i]);
    W2t[c * 128 + k] = f2bf(W2[i]);
  }
  __syncthreads();

  const int lane = threadIdx.x & 63;
  const int wave = threadIdx.x >> 6;
  const int col0 = lane & 15;
  const int kg   = lane >> 4;

  bf16x8 B1f[8][4];
  #pragma unroll
  for (int ct = 0; ct < 8; ct++)
    #pragma unroll
    for (int s = 0; s < 4; s++)
      B1f[ct][s] = *(const bf16x8*)&W1t[(ct * 16 + col0) * 128 + s * 32 + kg * 8];

  float bs1[8], bs2[8];
  #pragma unroll
  for (int ct = 0; ct < 8; ct++){ bs1[ct] = b1[ct * 16 + col0]; bs2[ct] = b2[ct * 16 + col0]; }

  const long tiles = ((long)M + 63) >> 6;
  for (long t = blockIdx.x; t < tiles; t += gridDim.x){
    const long rbase = t * 64 + wave * 16;
    const long arow  = rbase + col0;
    const float* Xp = X + (arow < M ? arow : 0) * D;
    float xm = 0.f, xr = 1.f;
    if (NORM && arow < M){ int g = batch[arow]; xm = meanG[g]; xr = rstdG[g]; }

    bf16x8 Af[4];
    #pragma unroll
    for (int s = 0; s < 4; s++){
      const int kb = s * 32 + kg * 8;
      float4 lo = *(const float4*)(Xp + kb);
      float4 hi = *(const float4*)(Xp + kb + 4);
      bf16x8 a;
      a[0]=f2bf((lo.x-xm)*xr); a[1]=f2bf((lo.y-xm)*xr); a[2]=f2bf((lo.z-xm)*xr); a[3]=f2bf((lo.w-xm)*xr);
      a[4]=f2bf((hi.x-xm)*xr); a[5]=f2bf((hi.y-xm)*xr); a[6]=f2bf((hi.z-xm)*xr); a[7]=f2bf((hi.w-xm)*xr);
      Af[s] = a;
    }

    f32x4 acc[8];
    #pragma unroll
    for (int ct = 0; ct < 8; ct++){ acc[ct][0]=0.f; acc[ct][1]=0.f; acc[ct][2]=0.f; acc[ct][3]=0.f; }
    #pragma unroll
    for (int ct = 0; ct < 8; ct++)
      #pragma unroll
      for (int s = 0; s < 4; s++)
        acc[ct] = __builtin_amdgcn_mfma_f32_16x16x32_bf16(Af[s], B1f[ct][s], acc[ct], 0, 0, 0);

    #pragma unroll
    for (int ct = 0; ct < 8; ct++){
      const int c = ct * 16 + col0;
      #pragma unroll
      for (int r = 0; r < 4; r++){
        const int row = wave * 16 + kg * 4 + r;
        const int gg = (c >> 3) ^ (row & 7);
        Ts[row * 128 + gg * 8 + (c & 7)] = f2bf(siluf(acc[ct][r] + bs1[ct]));
      }
    }
    __syncthreads();

    const int row2 = wave * 16 + col0;
    bf16x8 A2f[4];
    #pragma unroll
    for (int s = 0; s < 4; s++){
      const int chunk = (s * 4 + kg) ^ (row2 & 7);
      A2f[s] = *(const bf16x8*)&Ts[row2 * 128 + chunk * 8];
    }
    __syncthreads();

    #pragma unroll
    for (int ct = 0; ct < 8; ct++){ acc[ct][0]=0.f; acc[ct][1]=0.f; acc[ct][2]=0.f; acc[ct][3]=0.f; }
    #pragma unroll
    for (int ct = 0; ct < 8; ct++){
      bf16x8 B2v[4];
      #pragma unroll
      for (int s = 0; s < 4; s++)
        B2v[s] = *(const bf16x8*)&W2t[(ct * 16 + col0) * 128 + s * 32 + kg * 8];
      #pragma unroll
      for (int s = 0; s < 4; s++)
        acc[ct] = __builtin_amdgcn_mfma_f32_16x16x32_bf16(A2f[s], B2v[s], acc[ct], 0, 0, 0);
    }

    #pragma unroll
    for (int r = 0; r < 4; r++){
      const long orow = rbase + kg * 4 + r;
      if (orow >= M) continue;
      float rm = 0.f, rr = 1.f;
      if (NORM){ int g = batch[orow]; rm = meanG[g]; rr = rstdG[g]; }
      #pragma unroll
      for (int ct = 0; ct < 8; ct++){
        const int c = ct * 16 + col0;
        float base = X[orow * D + c];
        if (NORM) base = (base - rm) * rr;
        Y[orow * D + c] = base + siluf(acc[ct][r] + bs2[ct]);
      }
    }
  }
}

// ---------- fused readout MLP: results[r] += silu(silu(X@W1+b1)@W2+b2) . w3 + b3 ----------
__global__ __launch_bounds__(256, 2) void k_read2(
    const float* __restrict__ X,
    const float* __restrict__ W1, const float* __restrict__ b1,
    const float* __restrict__ W2, const float* __restrict__ b2,
    const float* __restrict__ w3, const float* __restrict__ b3,
    float* __restrict__ results, int M)
{
  __shared__ short W1t[128 * 128];
  __shared__ short W2t[128 * 128];
  __shared__ short Ts[64 * 128];
  for (int i = threadIdx.x; i < 128 * 128; i += 256){
    int k = i >> 7, c = i & 127;
    W1t[c * 128 + k] = f2bf(W1[i]);
    W2t[c * 128 + k] = f2bf(W2[i]);
  }
  __syncthreads();

  const int lane = threadIdx.x & 63;
  const int wave = threadIdx.x >> 6;
  const int col0 = lane & 15;
  const int kg   = lane >> 4;

  bf16x8 B1f[8][4];
  #pragma unroll
  for (int ct = 0; ct < 8; ct++)
    #pragma unroll
    for (int s = 0; s < 4; s++)
      B1f[ct][s] = *(const bf16x8*)&W1t[(ct * 16 + col0) * 128 + s * 32 + kg * 8];

  float bs1[8], bs2[8], w3v[8];
  #pragma unroll
  for (int ct = 0; ct < 8; ct++){
    bs1[ct] = b1[ct * 16 + col0];
    bs2[ct] = b2[ct * 16 + col0];
    w3v[ct] = w3[ct * 16 + col0];
  }
  const float b3v = b3[0];

  const long tiles = ((long)M + 63) >> 6;
  for (long t = blockIdx.x; t < tiles; t += gridDim.x){
    const long rbase = t * 64 + wave * 16;
    const long arow  = rbase + col0;
    const float* Xp = X + (arow < M ? arow : 0) * D;

    bf16x8 Af[4];
    #pragma unroll
    for (int s = 0; s < 4; s++){
      const int kb = s * 32 + kg * 8;
      float4 lo = *(const float4*)(Xp + kb);
      float4 hi = *(const float4*)(Xp + kb + 4);
      bf16x8 a;
      a[0]=f2bf(lo.x); a[1]=f2bf(lo.y); a[2]=f2bf(lo.z); a[3]=f2bf(lo.w);
      a[4]=f2bf(hi.x); a[5]=f2bf(hi.y); a[6]=f2bf(hi.z); a[7]=f2bf(hi.w);
      Af[s] = a;
    }

    f32x4 acc[8];
    #pragma unroll
    for (int ct = 0; ct < 8; ct++){ acc[ct][0]=0.f; acc[ct][1]=0.f; acc[ct][2]=0.f; acc[ct][3]=0.f; }
    #pragma unroll
    for (int ct = 0; ct < 8; ct++)
      #pragma unroll
      for (int s = 0; s < 4; s++)
        acc[ct] = __builtin_amdgcn_mfma_f32_16x16x32_bf16(Af[s], B1f[ct][s], acc[ct], 0, 0, 0);

    #pragma unroll
    for (int ct = 0; ct < 8; ct++){
      const int c = ct * 16 + col0;
      #pragma unroll
      for (int r = 0; r < 4; r++){
        const int row = wave * 16 + kg * 4 + r;
        const int gg = (c >> 3) ^ (row & 7);
        Ts[row * 128 + gg * 8 + (c & 7)] = f2bf(siluf(acc[ct][r] + bs1[ct]));
      }
    }
    __syncthreads();

    const int row2 = wave * 16 + col0;
    bf16x8 A2f[4];
    #pragma unroll
    for (int s = 0; s < 4; s++){
      const int chunk = (s * 4 + kg) ^ (row2 & 7);
      A2f[s] = *(const bf16x8*)&Ts[row2 * 128 + chunk * 8];
    }
    __syncthreads();

    #pragma unroll
    for (int ct = 0; ct < 8; ct++){ acc[ct][0]=0.f; acc[ct][1]=0.f; acc[ct][2]=0.f; acc[ct][3]=0.f; }
    #pragma unroll
    for (int ct = 0; ct < 8; ct++){
      bf16x8 B2v[4];
      #pragma unroll
      for (int s = 0; s < 4; s++)
        B2v[s] = *(const bf16x8*)&W2t[(ct * 16 + col0) * 128 + s * 32 + kg * 8];
      #pragma unroll
      for (int s = 0; s < 4; s++)
        acc[ct] = __builtin_amdgcn_mfma_f32_16x16x32_bf16(A2f[s], B2v[s], acc[ct], 0, 0, 0);
    }

    #pragma unroll
    for (int r = 0; r < 4; r++){
      float vr = 0.f;
      #pragma unroll
      for (int ct = 0; ct < 8; ct++)
        vr += siluf(acc[ct][r] + bs2[ct]) * w3v[ct];
      #pragma unroll
      for (int off = 1; off < 16; off <<= 1) vr += __shfl_xor(vr, off, 64);
      const long orow = rbase + kg * 4 + r;
      if (col0 == 0 && orow < M) results[orow] += vr + b3v;
    }
  }
}

// ---------- CSR build ----------
__global__ void k_hist(const int* __restrict__ idx, int* __restrict__ cnt, int M)
{
  for (long i = (long)blockIdx.x * 256 + threadIdx.x; i < M; i += (long)gridDim.x * 256)
    atomicAdd(&cnt[idx[i]], 1);
}

__global__ void k_scan(const int* __restrict__ cnt, int* __restrict__ rowptr, int M)
{
  __shared__ int buf[1024];
  const int tid = threadIdx.x;
  const int PT = 16;
  int carry = 0;
  for (int base = 0; base < M; base += 1024 * PT){
    int loc[PT]; int s = 0;
    #pragma unroll
    for (int j = 0; j < PT; j++){
      int i = base + tid * PT + j;
      loc[j] = (i < M) ? cnt[i] : 0;
      s += loc[j];
    }
    buf[tid] = s; __syncthreads();
    for (int off = 1; off < 1024; off <<= 1){
      int t = (tid >= off) ? buf[tid - off] : 0;
      __syncthreads();
      buf[tid] += t;
      __syncthreads();
    }
    int run = buf[tid] - s + carry;
    carry += buf[1023];
    __syncthreads();
    #pragma unroll
    for (int j = 0; j < PT; j++){
      int i = base + tid * PT + j;
      if (i < M) rowptr[i] = run;
      run += loc[j];
    }
  }
  if (tid == 0) rowptr[M] = carry;
}

__global__ void k_fill(const int* __restrict__ idx, const int* __restrict__ rowptr,
                       int* __restrict__ cursor, int* __restrict__ ids, int M)
{
  for (long i = (long)blockIdx.x * 256 + threadIdx.x; i < M; i += (long)gridDim.x * 256){
    int sgm = idx[i];
    int pos = atomicAdd(&cursor[sgm], 1);
    ids[rowptr[sgm] + pos] = (int)i;
  }
}

// invD[eids[i]] = i; srcCSR[i] = srcA[eids[i]]
__global__ void k_invsrc(const int* __restrict__ eids, const int* __restrict__ srcA,
                         int* __restrict__ invD, int* __restrict__ srcCSR, int E_)
{
  for (long i = (long)blockIdx.x * 256 + threadIdx.x; i < E_; i += (long)gridDim.x * 256){
    int e = eids[i];
    invD[e] = (int)i;
    srcCSR[i] = srcA[e];
  }
}

// ---------- CSR gather-sum (atoms_rep) ----------
__global__ __launch_bounds__(256) void k_gather_sum(
    const float* __restrict__ X, const int* __restrict__ rowptr,
    const int* __restrict__ ids, float* __restrict__ Yat, int A_)
{
  const int lane = threadIdx.x & 63;
  const int wv   = threadIdx.x >> 6;
  for (long a = (long)blockIdx.x * 4 + wv; a < A_; a += (long)gridDim.x * 4){
    int beg = rowptr[a], end = rowptr[a + 1];
    float a0 = 0.f, a1 = 0.f;
    for (int i = beg; i < end; i++){
      const float* xp = X + (long)ids[i] * D;
      a0 += xp[lane]; a1 += xp[lane + 64];
    }
    Yat[a * D + lane] = a0; Yat[a * D + lane + 64] = a1;
  }
}

// ---------- CSR gather with rbf gate (readout scatter) ----------
__global__ __launch_bounds__(256) void k_gather_gate_sum(
    const float* __restrict__ X, const float* __restrict__ rbf,
    const float* __restrict__ Wr, const int* __restrict__ rowptr,
    const int* __restrict__ ids, float* __restrict__ Yat, int A_)
{
  __shared__ float Wrs[RBFD * D];
  for (int i = threadIdx.x; i < RBFD * D; i += 256) Wrs[i] = Wr[i];
  __syncthreads();
  const int lane = threadIdx.x & 63;
  const int wv   = threadIdx.x >> 6;
  for (long a = (long)blockIdx.x * 4 + wv; a < A_; a += (long)gridDim.x * 4){
    int beg = rowptr[a], end = rowptr[a + 1];
    float a0 = 0.f, a1 = 0.f;
    for (int i = beg; i < end; i++){
      long n = ids[i];
      const float* xp = X + n * D;
      const float* rb = rbf + n * RBFD;
      float g0 = 0.f, g1 = 0.f;
      #pragma unroll
      for (int r = 0; r < RBFD; r++){
        float rv = rb[r];
        g0 += rv * Wrs[r * D + lane];
        g1 += rv * Wrs[r * D + lane + 64];
      }
      a0 += xp[lane] * g0; a1 += xp[lane + 64] * g1;
    }
    Yat[a * D + lane] = a0; Yat[a * D + lane + 64] = a1;
  }
}

// ---------- fused attention ----------
__device__ __forceinline__ void attn_step(long i, const int* __restrict__ srcCSR,
    const float* __restrict__ k, const float* __restrict__ v,
    const float* __restrict__ ek, const float* __restrict__ sw, int lane,
    float q0, float q1, float& m0, float& m1, float& l0, float& l1, float& a0, float& a1)
{
  const long s = srcCSR[i];
  const float* kp = k + s * D;
  const float* vp = v + s * D;
  const float* ep = ek + i * D;
  const float* sp = sw + i * D;
  float e0 = ep[lane], e1 = ep[lane + 64];
  float t0 = q0 * (kp[lane] + e0), t1 = q1 * (kp[lane + 64] + e1);
  #pragma unroll
  for (int off = 1; off < 16; off <<= 1){
    t0 += __shfl_xor(t0, off, 64);
    t1 += __shfl_xor(t1, off, 64);
  }
  t0 *= 0.25f; t1 *= 0.25f;
  float u0 = (vp[lane] + e0) * sp[lane];
  float u1 = (vp[lane + 64] + e1) * sp[lane + 64];
  float nm0 = fmaxf(m0, t0), nm1 = fmaxf(m1, t1);
  float sc0 = __expf(m0 - nm0), sc1 = __expf(m1 - nm1);
  float w0 = __expf(t0 - nm0), w1 = __expf(t1 - nm1);
  l0 = l0 * sc0 + w0;  a0 = a0 * sc0 + w0 * u0;  m0 = nm0;
  l1 = l1 * sc1 + w1;  a1 = a1 * sc1 + w1 * u1;  m1 = nm1;
}

// one wave per dst node; ek/sw pre-permuted to CSR order; h over q in place.
__global__ __launch_bounds__(256) void k_attn(
    float* __restrict__ q, const float* __restrict__ k, const float* __restrict__ v,
    const float* __restrict__ ek, const float* __restrict__ sw,
    const int* __restrict__ rowptr, const int* __restrict__ srcCSR,
    const float* __restrict__ rbf, const float* __restrict__ Wr,
    const int* __restrict__ batch,
    double* __restrict__ sums, double* __restrict__ sumsq, int Nn)
{
  __shared__ float Wrs[RBFD * D];
  for (int i = threadIdx.x; i < RBFD * D; i += 256) Wrs[i] = Wr[i];
  __syncthreads();
  const int lane = threadIdx.x & 63;
  const int wv   = threadIdx.x >> 6;
  for (long d = (long)blockIdx.x * 4 + wv; d < Nn; d += (long)gridDim.x * 4){
    const int beg = rowptr[d], end = rowptr[d + 1];
    const float q0 = q[d * D + lane], q1 = q[d * D + lane + 64];
    float mA0=-1e30f, mA1=-1e30f, lA0=0.f, lA1=0.f, aA0=0.f, aA1=0.f;
    float mB0=-1e30f, mB1=-1e30f, lB0=0.f, lB1=0.f, aB0=0.f, aB1=0.f;
    int i = beg;
    for (; i + 1 < end; i += 2){
      attn_step(i,     srcCSR, k, v, ek, sw, lane, q0, q1, mA0, mA1, lA0, lA1, aA0, aA1);
      attn_step(i + 1, srcCSR, k, v, ek, sw, lane, q0, q1, mB0, mB1, lB0, lB1, aB0, aB1);
    }
    if (i < end)
      attn_step(i, srcCSR, k, v, ek, sw, lane, q0, q1, mA0, mA1, lA0, lA1, aA0, aA1);
    // merge chains
    float nm0 = fmaxf(mA0, mB0), nm1 = fmaxf(mA1, mB1);
    float sA0 = __expf(mA0 - nm0), sB0 = __expf(mB0 - nm0);
    float sA1 = __expf(mA1 - nm1), sB1 = __expf(mB1 - nm1);
    float l0 = lA0 * sA0 + lB0 * sB0, l1 = lA1 * sA1 + lB1 * sB1;
    float a0 = aA0 * sA0 + aB0 * sB0, a1 = aA1 * sA1 + aB1 * sB1;
    a0 /= (l0 + 1e-16f); a1 /= (l1 + 1e-16f);
    // rbf gate
    const float* rb = rbf + d * RBFD;
    float g0 = 0.f, g1 = 0.f;
    #pragma unroll
    for (int r = 0; r < RBFD; r++){
      float rv = rb[r];
      g0 += rv * Wrs[r * D + lane];
      g1 += rv * Wrs[r * D + lane + 64];
    }
    a0 *= g0; a1 *= g1;
    q[d * D + lane] = a0; q[d * D + lane + 64] = a1;
    // graph-norm stats
    float ss = a0 + a1, qq = a0 * a0 + a1 * a1;
    #pragma unroll
    for (int off = 1; off < 64; off <<= 1){
      ss += __shfl_xor(ss, off, 64);
      qq += __shfl_xor(qq, off, 64);
    }
    if (lane == 0){
      int g = batch[d];
      atomicAdd(&sums[g], (double)ss);
      atomicAdd(&sumsq[g], (double)qq);
    }
  }
}

// ---------- graph norm ----------
__global__ void k_count(const int* __restrict__ batch, int* __restrict__ cnt, int M)
{
  for (long i = (long)blockIdx.x * 256 + threadIdx.x; i < M; i += (long)gridDim.x * 256)
    atomicAdd(&cnt[batch[i]], 1);
}

__global__ void k_norm_final(const double* __restrict__ sums, const double* __restrict__ sumsq,
                             const int* __restrict__ cnt, float* __restrict__ meanG,
                             float* __restrict__ rstdG)
{
  int g = threadIdx.x;
  double c = (double)cnt[g] * (double)D;
  double mean = sums[g] / c;
  double var = sumsq[g] / c - mean * mean;
  meanG[g] = (float)mean;
  rstdG[g] = (float)(1.0 / sqrt(var + 1e-8));
}

__global__ void k_final(const float* __restrict__ results, const int* __restrict__ ab,
                        float* __restrict__ out, int A_)
{
  int i = blockIdx.x * 256 + threadIdx.x;
  if (i < A_) atomicAdd(&out[ab[i]], results[i] / 3.0f);
}

// ---------- fold w2@we, b2@we ----------
__global__ void k_w2e(const float* __restrict__ w2, const float* __restrict__ we,
                      float* __restrict__ W2e)
{
  int i = blockIdx.x >> 7;
  int r = blockIdx.x & 127;
  int c = threadIdx.x;
  const float* w2p = w2 + (size_t)i * D * D + (size_t)r * D;
  const float* wep = we + (size_t)i * D * D;
  float acc = 0.f;
  for (int j = 0; j < D; j++) acc += w2p[j] * wep[j * D + c];
  W2e[(size_t)i * D * D + (size_t)r * D + c] = acc;
}

__global__ void k_b2e(const float* __restrict__ b2, const float* __restrict__ we,
                      float* __restrict__ B2e)
{
  int i = blockIdx.x; int c = threadIdx.x;
  float acc = 0.f;
  for (int j = 0; j < D; j++) acc += b2[(size_t)i * D + j] * we[(size_t)i * D * D + j * D + c];
  B2e[(size_t)i * D + c] = acc;
}

extern "C" void kernel_launch(void* const* d_in, const int* in_sizes, int n_in,
                              void* d_out, int out_size, void* d_ws, size_t ws_size,
                              hipStream_t stream)
{
  const float* x          = (const float*)d_in[0];
  const float* node_rbf   = (const float*)d_in[1];
  const float* edge_sbf   = (const float*)d_in[2];
  const int*   edge_index = (const int*)d_in[3];
  const int*   pair_idx   = (const int*)d_in[4];
  const int*   eidx0      = (const int*)d_in[5];
  const int*   atom_batch = (const int*)d_in[6];
  const int*   batch      = (const int*)d_in[7];
  const float* edgenn_w1  = (const float*)d_in[8];
  const float* edgenn_b1  = (const float*)d_in[9];
  const float* edgenn_w2  = (const float*)d_in[10];
  const float* edgenn_b2  = (const float*)d_in[11];
  const float* conv_wq    = (const float*)d_in[12];
  const float* conv_wk    = (const float*)d_in[13];
  const float* conv_wv    = (const float*)d_in[14];
  const float* conv_we    = (const float*)d_in[15];
  const float* conv_wsbf  = (const float*)d_in[16];
  const float* conv_bsbf  = (const float*)d_in[17];
  const float* conv_wrbf  = (const float*)d_in[18];
  const float* dense_w    = (const float*)d_in[19];
  const float* dense_b    = (const float*)d_in[20];
  const float* bf_w       = (const float*)d_in[21];
  const float* bf_b       = (const float*)d_in[22];
  const float* af_w       = (const float*)d_in[23];
  const float* af_b       = (const float*)d_in[24];
  const float* read_wrbf  = (const float*)d_in[25];
  const float* read_w1    = (const float*)d_in[26];
  const float* read_b1    = (const float*)d_in[27];
  const float* read_w2    = (const float*)d_in[28];
  const float* read_b2    = (const float*)d_in[29];
  const float* read_w3    = (const float*)d_in[30];
  const float* read_b3    = (const float*)d_in[31];

  const int N = in_sizes[0] / D;
  const int E = in_sizes[4];
  const int A = in_sizes[6];
  const int G = out_size;

  char* p = (char*)d_ws;
  auto carve = [&](size_t bytes)->char*{ char* r = p; p += (bytes + 255) & ~(size_t)255; return r; };
  float*    EbufA   = (float*)carve((size_t)E * D * 4);   // sw (CSR order)
  float*    EbufB   = (float*)carve((size_t)E * D * 4);   // ek (CSR order)
  float*    ping0   = (float*)carve((size_t)N * D * 4);
  float*    ping1   = (float*)carve((size_t)N * D * 4);
  float*    bq      = (float*)carve((size_t)N * D * 4);   // q -> h
  float*    bk      = (float*)carve((size_t)N * D * 4);
  float*    bv      = (float*)carve((size_t)N * D * 4);
  float*    bufAtoms= (float*)carve((size_t)A * D * 4);
  float*    results = (float*)carve((size_t)A * 4);
  double*   sumG    = (double*)carve((size_t)G * 8);
  double*   sumsqG  = (double*)carve((size_t)G * 8);
  int*      cntG    = (int*)carve((size_t)G * 4);
  float*    meanG   = (float*)carve((size_t)G * 4);
  float*    rstdG   = (float*)carve((size_t)G * 4);
  float*    W2e     = (float*)carve((size_t)LAYERS * D * D * 4);
  float*    B2e     = (float*)carve((size_t)LAYERS * D * 4);
  int*      rowptrD = (int*)carve((size_t)(N + 1) * 4);
  int*      eidsD   = (int*)carve((size_t)E * 4);
  int*      invD    = (int*)carve((size_t)E * 4);
  int*      srcCSR  = (int*)carve((size_t)E * 4);
  int*      cntD    = (int*)carve((size_t)N * 4);
  int*      rowptrA = (int*)carve((size_t)(A + 1) * 4);
  int*      idsA    = (int*)carve((size_t)N * 4);
  int*      cntA    = (int*)carve((size_t)A * 4);

  const int* srcA = edge_index;
  const int* dstA = edge_index + E;

  auto ew_grid = [](long total){ long b = (total + 255) / 256; return (int)(b < 4096 ? b : 4096); };
  auto gemm_grid = [](int M){ long t = ((long)M + 63) / 64; return (int)(t < 1024 ? t : 1024); };
  const int gridAttn = (N + 3) / 4;
  const int gridAtom = (A + 3) / 4;

  // ---- one-time setup ----
  hipMemsetAsync(cntG, 0, (size_t)G * 4, stream);
  hipMemsetAsync(results, 0, (size_t)A * 4, stream);
  hipMemsetAsync(d_out, 0, (size_t)G * 4, stream);
  k_count<<<ew_grid(N), 256, 0, stream>>>(batch, cntG, N);
  k_w2e<<<LAYERS * D, D, 0, stream>>>(edgenn_w2, conv_we, W2e);
  k_b2e<<<LAYERS, D, 0, stream>>>(edgenn_b2, conv_we, B2e);
  // CSR by dst (edges)
  hipMemsetAsync(cntD, 0, (size_t)N * 4, stream);
  k_hist<<<ew_grid(E), 256, 0, stream>>>(dstA, cntD, E);
  k_scan<<<1, 1024, 0, stream>>>(cntD, rowptrD, N);
  hipMemsetAsync(cntD, 0, (size_t)N * 4, stream);
  k_fill<<<ew_grid(E), 256, 0, stream>>>(dstA, rowptrD, cntD, eidsD, E);
  k_invsrc<<<ew_grid(E), 256, 0, stream>>>(eidsD, srcA, invD, srcCSR, E);
  // CSR by atom (nodes)
  hipMemsetAsync(cntA, 0, (size_t)A * 4, stream);
  k_hist<<<ew_grid(N), 256, 0, stream>>>(eidx0, cntA, N);
  k_scan<<<1, 1024, 0, stream>>>(cntA, rowptrA, A);
  hipMemsetAsync(cntA, 0, (size_t)A * 4, stream);
  k_fill<<<ew_grid(N), 256, 0, stream>>>(eidx0, rowptrA, cntA, idsA, N);

  auto readout = [&](int i, const float* hbuf){
    k_gather_gate_sum<<<gridAtom, 256, 0, stream>>>(hbuf, node_rbf, read_wrbf + (size_t)i * RBFD * D,
                                                    rowptrA, idsA, bufAtoms, A);
    k_read2<<<gemm_grid(A), 256, 0, stream>>>(bufAtoms,
        read_w1 + (size_t)i*D*D, read_b1 + (size_t)i*D,
        read_w2 + (size_t)i*D*D, read_b2 + (size_t)i*D,
        read_w3 + (size_t)i*D, read_b3 + i, results, A);
  };

  readout(0, x);

  const float* cur = x;
  float* pp[2] = {ping0, ping1};
  for (int i = 0; i < LAYERS; i++){
    float* nxt = pp[i & 1];
    const size_t oDD = (size_t)i * D * D;
    // atoms_rep = segsum(cur, eidx0)  (CSR gather)
    k_gather_sum<<<gridAtom, 256, 0, stream>>>(cur, rowptrA, idsA, bufAtoms, A);
    // ek = silu(atoms_rep[pair_idx]@w1+b1) @ (w2@we) + b2@we   (fused, CSR-permuted out)
    k_gemm2<<<gemm_grid(E),256,0,stream>>>(bufAtoms, pair_idx, edgenn_w1 + oDD, edgenn_b1 + (size_t)i*D,
                                           W2e + oDD, B2e + (size_t)i*D, EbufB, invD, E);
    // q, k, v
    k_gemm<D,0,false,false,false,false><<<gemm_grid(N),256,0,stream>>>(cur, nullptr, conv_wq + oDD, nullptr, nullptr, bq, nullptr, N);
    k_gemm<D,0,false,false,false,false><<<gemm_grid(N),256,0,stream>>>(cur, nullptr, conv_wk + oDD, nullptr, nullptr, bk, nullptr, N);
    k_gemm<D,0,false,false,false,false><<<gemm_grid(N),256,0,stream>>>(cur, nullptr, conv_wv + oDD, nullptr, nullptr, bv, nullptr, N);
    // sw = edge_sbf @ wsbf + bsbf  (CSR-permuted out)
    k_gemm<SBFD,0,false,true,false,true><<<gemm_grid(E),256,0,stream>>>(edge_sbf, nullptr, conv_wsbf + (size_t)i*SBFD*D, conv_bsbf + (size_t)i*D, nullptr, EbufA, invD, E);
    // fused attention + rbf gate + stats; h written over bq
    hipMemsetAsync(sumG, 0, (size_t)G * 16, stream);   // covers sumG + sumsqG (adjacent)
    k_attn<<<gridAttn, 256, 0, stream>>>(bq, bk, bv, EbufB, EbufA, rowptrD, srcCSR,
                                         node_rbf, conv_wrbf + (size_t)i*RBFD*D, batch,
                                         sumG, sumsqG, N);
    k_norm_final<<<1, G, 0, stream>>>(sumG, sumsqG, cntG, meanG, rstdG);
    // bf residual block (absorbs norm-apply), in place on bq
    k_res2<true><<<gemm_grid(N),256,0,stream>>>(bq, bf_w + (size_t)i*2*D*D, bf_b + (size_t)i*2*D,
                                                bf_w + (size_t)i*2*D*D + D*D, bf_b + (size_t)i*2*D + D,
                                                batch, meanG, rstdG, bq, N);
    // dense + res0
    k_gemm<D,1,false,true,true,false><<<gemm_grid(N),256,0,stream>>>(bq, nullptr, dense_w + oDD, dense_b + (size_t)i*D, cur, nxt, nullptr, N);
    // af residual blocks, in place on nxt
    k_res2<false><<<gemm_grid(N),256,0,stream>>>(nxt, af_w + (size_t)i*4*D*D,         af_b + (size_t)i*4*D,
                                                 af_w + (size_t)i*4*D*D + D*D,       af_b + (size_t)i*4*D + D,
                                                 nullptr, nullptr, nullptr, nxt, N);
    k_res2<false><<<gemm_grid(N),256,0,stream>>>(nxt, af_w + (size_t)i*4*D*D + 2*D*D, af_b + (size_t)i*4*D + 2*D,
                                                 af_w + (size_t)i*4*D*D + 3*D*D,     af_b + (size_t)i*4*D + 3*D,
                                                 nullptr, nullptr, nullptr, nxt, N);
    // readout
    readout(i + 1, nxt);
    cur = nxt;
  }
  k_final<<<(A + 255) / 256, 256, 0, stream>>>(results, atom_batch, (float*)d_out, A);
}

// Round 5
// 3131.597 us; speedup vs baseline: 2.2906x; 1.0393x over previous
//
#include <hip/hip_runtime.h>
#include <math.h>

#define D    128
#define NH   8
#define RBFD 16
#define SBFD 112
#define LAYERS 3

typedef __attribute__((ext_vector_type(8))) short bf16x8;
typedef __attribute__((ext_vector_type(4))) float f32x4;

__device__ __forceinline__ float siluf(float x){ return x / (1.0f + __expf(-x)); }

__device__ __forceinline__ short f2bf(float f){
  union { float f; unsigned u; } v; v.f = f;
  unsigned r = v.u + 0x7FFFu + ((v.u >> 16) & 1u);   // RNE
  return (short)(r >> 16);
}
__device__ __forceinline__ float bflo(unsigned u){ return __uint_as_float(u << 16); }
__device__ __forceinline__ float bfhi(unsigned u){ return __uint_as_float(u & 0xFFFF0000u); }

// ---------- MFMA GEMM: Y[M,128] = epilogue(X[gather?][.,DIN] @ W[DIN,128]) ----------
template<int DIN, int ACT, bool GATHER, bool HASB, bool HASRES, bool PERM, bool OUTBF>
__global__ __launch_bounds__(256, 2) void k_gemm(
    const float* __restrict__ X, const int* __restrict__ gidx,
    const float* __restrict__ W, const float* __restrict__ bias,
    const float* res, void* __restrict__ Yv, const int* __restrict__ operm, int M)
{
  __shared__ short Wt[128 * 128];          // transposed bf16 weights: Wt[col][k]
  if (DIN < 128){
    for (int i = threadIdx.x; i < 128 * 128; i += 256) Wt[i] = 0;
    __syncthreads();
  }
  for (int i = threadIdx.x; i < DIN * 128; i += 256){
    int k = i >> 7, c = i & 127;
    Wt[c * 128 + k] = f2bf(W[i]);
  }
  __syncthreads();

  const int lane = threadIdx.x & 63;
  const int wave = threadIdx.x >> 6;
  const int col0 = lane & 15;
  const int kg   = lane >> 4;

  bf16x8 Bf[8][4];
  #pragma unroll
  for (int ct = 0; ct < 8; ct++)
    #pragma unroll
    for (int s = 0; s < 4; s++)
      Bf[ct][s] = *(const bf16x8*)&Wt[(ct * 16 + col0) * 128 + s * 32 + kg * 8];

  float bs[8];
  if (HASB){
    #pragma unroll
    for (int ct = 0; ct < 8; ct++) bs[ct] = bias[ct * 16 + col0];
  }

  float* __restrict__ Yf = (float*)Yv;
  unsigned short* __restrict__ Yb = (unsigned short*)Yv;

  const long tiles = ((long)M + 63) >> 6;
  for (long t = blockIdx.x; t < tiles; t += gridDim.x){
    const long rbase = t * 64 + wave * 16;
    const long arow  = rbase + col0;
    long srow = 0;
    if (arow < M) srow = GATHER ? (long)gidx[arow] : arow;
    const float* Xp = X + srow * DIN;

    bf16x8 Af[4];
    #pragma unroll
    for (int s = 0; s < 4; s++){
      const int kb = s * 32 + kg * 8;
      bf16x8 a;
      if (DIN == 128 || kb + 8 <= DIN){
        float4 lo = *(const float4*)(Xp + kb);
        float4 hi = *(const float4*)(Xp + kb + 4);
        a[0]=f2bf(lo.x); a[1]=f2bf(lo.y); a[2]=f2bf(lo.z); a[3]=f2bf(lo.w);
        a[4]=f2bf(hi.x); a[5]=f2bf(hi.y); a[6]=f2bf(hi.z); a[7]=f2bf(hi.w);
      } else {
        #pragma unroll
        for (int j = 0; j < 8; j++) a[j] = 0;
      }
      Af[s] = a;
    }

    f32x4 acc[8];
    #pragma unroll
    for (int ct = 0; ct < 8; ct++){ acc[ct][0]=0.f; acc[ct][1]=0.f; acc[ct][2]=0.f; acc[ct][3]=0.f; }
    #pragma unroll
    for (int ct = 0; ct < 8; ct++)
      #pragma unroll
      for (int s = 0; s < 4; s++)
        acc[ct] = __builtin_amdgcn_mfma_f32_16x16x32_bf16(Af[s], Bf[ct][s], acc[ct], 0, 0, 0);

    #pragma unroll
    for (int r = 0; r < 4; r++){
      const long orow = rbase + kg * 4 + r;
      if (orow >= M) continue;
      const long wrow = PERM ? (long)operm[orow] : orow;
      #pragma unroll
      for (int ct = 0; ct < 8; ct++){
        const int c = ct * 16 + col0;
        float v = acc[ct][r];
        if (HASB) v += bs[ct];
        if (ACT)  v = siluf(v);
        if (HASRES) v += res[orow * D + c];
        if (OUTBF) Yb[wrow * D + c] = (unsigned short)f2bf(v);
        else       Yf[wrow * D + c] = v;
      }
    }
  }
}

// ---------- fused edgenn: ek = silu(X[gidx]@W1+b1) @ W2 + b2 -> bf16, permuted ----------
__global__ __launch_bounds__(256, 2) void k_gemm2(
    const float* __restrict__ X, const int* __restrict__ gidx,
    const float* __restrict__ W1, const float* __restrict__ b1,
    const float* __restrict__ W2, const float* __restrict__ b2,
    unsigned short* __restrict__ Y, const int* __restrict__ operm, int M)
{
  __shared__ short W1t[128 * 128];
  __shared__ short W2t[128 * 128];
  __shared__ short Ts[64 * 128];
  for (int i = threadIdx.x; i < 128 * 128; i += 256){
    int k = i >> 7, c = i & 127;
    W1t[c * 128 + k] = f2bf(W1[i]);
    W2t[c * 128 + k] = f2bf(W2[i]);
  }
  __syncthreads();

  const int lane = threadIdx.x & 63;
  const int wave = threadIdx.x >> 6;
  const int col0 = lane & 15;
  const int kg   = lane >> 4;

  bf16x8 B1f[8][4];
  #pragma unroll
  for (int ct = 0; ct < 8; ct++)
    #pragma unroll
    for (int s = 0; s < 4; s++)
      B1f[ct][s] = *(const bf16x8*)&W1t[(ct * 16 + col0) * 128 + s * 32 + kg * 8];

  float bs1[8], bs2[8];
  #pragma unroll
  for (int ct = 0; ct < 8; ct++){ bs1[ct] = b1[ct * 16 + col0]; bs2[ct] = b2[ct * 16 + col0]; }

  const long tiles = ((long)M + 63) >> 6;
  for (long t = blockIdx.x; t < tiles; t += gridDim.x){
    const long rbase = t * 64 + wave * 16;
    const long arow  = rbase + col0;
    long srow = 0;
    if (arow < M) srow = (long)gidx[arow];
    const float* Xp = X + srow * D;

    bf16x8 Af[4];
    #pragma unroll
    for (int s = 0; s < 4; s++){
      const int kb = s * 32 + kg * 8;
      float4 lo = *(const float4*)(Xp + kb);
      float4 hi = *(const float4*)(Xp + kb + 4);
      bf16x8 a;
      a[0]=f2bf(lo.x); a[1]=f2bf(lo.y); a[2]=f2bf(lo.z); a[3]=f2bf(lo.w);
      a[4]=f2bf(hi.x); a[5]=f2bf(hi.y); a[6]=f2bf(hi.z); a[7]=f2bf(hi.w);
      Af[s] = a;
    }

    f32x4 acc[8];
    #pragma unroll
    for (int ct = 0; ct < 8; ct++){ acc[ct][0]=0.f; acc[ct][1]=0.f; acc[ct][2]=0.f; acc[ct][3]=0.f; }
    #pragma unroll
    for (int ct = 0; ct < 8; ct++)
      #pragma unroll
      for (int s = 0; s < 4; s++)
        acc[ct] = __builtin_amdgcn_mfma_f32_16x16x32_bf16(Af[s], B1f[ct][s], acc[ct], 0, 0, 0);

    #pragma unroll
    for (int ct = 0; ct < 8; ct++){
      const int c = ct * 16 + col0;
      #pragma unroll
      for (int r = 0; r < 4; r++){
        const int row = wave * 16 + kg * 4 + r;
        const int gg = (c >> 3) ^ (row & 7);
        Ts[row * 128 + gg * 8 + (c & 7)] = f2bf(siluf(acc[ct][r] + bs1[ct]));
      }
    }
    __syncthreads();

    const int row2 = wave * 16 + col0;
    bf16x8 A2f[4];
    #pragma unroll
    for (int s = 0; s < 4; s++){
      const int chunk = (s * 4 + kg) ^ (row2 & 7);
      A2f[s] = *(const bf16x8*)&Ts[row2 * 128 + chunk * 8];
    }
    __syncthreads();

    #pragma unroll
    for (int ct = 0; ct < 8; ct++){ acc[ct][0]=0.f; acc[ct][1]=0.f; acc[ct][2]=0.f; acc[ct][3]=0.f; }
    #pragma unroll
    for (int ct = 0; ct < 8; ct++){
      bf16x8 B2v[4];
      #pragma unroll
      for (int s = 0; s < 4; s++)
        B2v[s] = *(const bf16x8*)&W2t[(ct * 16 + col0) * 128 + s * 32 + kg * 8];
      #pragma unroll
      for (int s = 0; s < 4; s++)
        acc[ct] = __builtin_amdgcn_mfma_f32_16x16x32_bf16(A2f[s], B2v[s], acc[ct], 0, 0, 0);
    }

    #pragma unroll
    for (int r = 0; r < 4; r++){
      const long orow = rbase + kg * 4 + r;
      if (orow >= M) continue;
      const long wrow = (long)operm[orow];
      #pragma unroll
      for (int ct = 0; ct < 8; ct++){
        const int c = ct * 16 + col0;
        Y[wrow * D + c] = (unsigned short)f2bf(acc[ct][r] + bs2[ct]);
      }
    }
  }
}

// ---------- fused residual block: Y = norm?(X) + silu(silu(norm?(X)@W1+b1)@W2+b2) ----------
template<bool NORM>
__global__ __launch_bounds__(256, 2) void k_res2(
    const float* __restrict__ X,
    const float* __restrict__ W1, const float* __restrict__ b1,
    const float* __restrict__ W2, const float* __restrict__ b2,
    const int* __restrict__ batch, const float* __restrict__ meanG,
    const float* __restrict__ rstdG, float* __restrict__ Y, int M)
{
  __shared__ short W1t[128 * 128];
  __shared__ short W2t[128 * 128];
  __shared__ short Ts[64 * 128];
  for (int i = threadIdx.x; i < 128 * 128; i += 256){
    int k = i >> 7, c = i & 127;
    W1t[c * 128 + k] = f2bf(W1[i]);
    W2t[c * 128 + k] = f2bf(W2[i]);
  }
  __syncthreads();

  const int lane = threadIdx.x & 63;
  const int wave = threadIdx.x >> 6;
  const int col0 = lane & 15;
  const int kg   = lane >> 4;

  bf16x8 B1f[8][4];
  #pragma unroll
  for (int ct = 0; ct < 8; ct++)
    #pragma unroll
    for (int s = 0; s < 4; s++)
      B1f[ct][s] = *(const bf16x8*)&W1t[(ct * 16 + col0) * 128 + s * 32 + kg * 8];

  float bs1[8], bs2[8];
  #pragma unroll
  for (int ct = 0; ct < 8; ct++){ bs1[ct] = b1[ct * 16 + col0]; bs2[ct] = b2[ct * 16 + col0]; }

  const long tiles = ((long)M + 63) >> 6;
  for (long t = blockIdx.x; t < tiles; t += gridDim.x){
    const long rbase = t * 64 + wave * 16;
    const long arow  = rbase + col0;
    const float* Xp = X + (arow < M ? arow : 0) * D;
    float xm = 0.f, xr = 1.f;
    if (NORM && arow < M){ int g = batch[arow]; xm = meanG[g]; xr = rstdG[g]; }

    bf16x8 Af[4];
    #pragma unroll
    for (int s = 0; s < 4; s++){
      const int kb = s * 32 + kg * 8;
      float4 lo = *(const float4*)(Xp + kb);
      float4 hi = *(const float4*)(Xp + kb + 4);
      bf16x8 a;
      a[0]=f2bf((lo.x-xm)*xr); a[1]=f2bf((lo.y-xm)*xr); a[2]=f2bf((lo.z-xm)*xr); a[3]=f2bf((lo.w-xm)*xr);
      a[4]=f2bf((hi.x-xm)*xr); a[5]=f2bf((hi.y-xm)*xr); a[6]=f2bf((hi.z-xm)*xr); a[7]=f2bf((hi.w-xm)*xr);
      Af[s] = a;
    }

    f32x4 acc[8];
    #pragma unroll
    for (int ct = 0; ct < 8; ct++){ acc[ct][0]=0.f; acc[ct][1]=0.f; acc[ct][2]=0.f; acc[ct][3]=0.f; }
    #pragma unroll
    for (int ct = 0; ct < 8; ct++)
      #pragma unroll
      for (int s = 0; s < 4; s++)
        acc[ct] = __builtin_amdgcn_mfma_f32_16x16x32_bf16(Af[s], B1f[ct][s], acc[ct], 0, 0, 0);

    #pragma unroll
    for (int ct = 0; ct < 8; ct++){
      const int c = ct * 16 + col0;
      #pragma unroll
      for (int r = 0; r < 4; r++){
        const int row = wave * 16 + kg * 4 + r;
        const int gg = (c >> 3) ^ (row & 7);
        Ts[row * 128 + gg * 8 + (c & 7)] = f2bf(siluf(acc[ct][r] + bs1[ct]));
      }
    }
    __syncthreads();

    const int row2 = wave * 16 + col0;
    bf16x8 A2f[4];
    #pragma unroll
    for (int s = 0; s < 4; s++){
      const int chunk = (s * 4 + kg) ^ (row2 & 7);
      A2f[s] = *(const bf16x8*)&Ts[row2 * 128 + chunk * 8];
    }
    __syncthreads();

    #pragma unroll
    for (int ct = 0; ct < 8; ct++){ acc[ct][0]=0.f; acc[ct][1]=0.f; acc[ct][2]=0.f; acc[ct][3]=0.f; }
    #pragma unroll
    for (int ct = 0; ct < 8; ct++){
      bf16x8 B2v[4];
      #pragma unroll
      for (int s = 0; s < 4; s++)
        B2v[s] = *(const bf16x8*)&W2t[(ct * 16 + col0) * 128 + s * 32 + kg * 8];
      #pragma unroll
      for (int s = 0; s < 4; s++)
        acc[ct] = __builtin_amdgcn_mfma_f32_16x16x32_bf16(A2f[s], B2v[s], acc[ct], 0, 0, 0);
    }

    #pragma unroll
    for (int r = 0; r < 4; r++){
      const long orow = rbase + kg * 4 + r;
      if (orow >= M) continue;
      float rm = 0.f, rr = 1.f;
      if (NORM){ int g = batch[orow]; rm = meanG[g]; rr = rstdG[g]; }
      #pragma unroll
      for (int ct = 0; ct < 8; ct++){
        const int c = ct * 16 + col0;
        float base = X[orow * D + c];
        if (NORM) base = (base - rm) * rr;
        Y[orow * D + c] = base + siluf(acc[ct][r] + bs2[ct]);
      }
    }
  }
}

// ---------- fused readout MLP: results[r] += silu(silu(X@W1+b1)@W2+b2) . w3 + b3 ----------
__global__ __launch_bounds__(256, 2) void k_read2(
    const float* __restrict__ X,
    const float* __restrict__ W1, const float* __restrict__ b1,
    const float* __restrict__ W2, const float* __restrict__ b2,
    const float* __restrict__ w3, const float* __restrict__ b3,
    float* __restrict__ results, int M)
{
  __shared__ short W1t[128 * 128];
  __shared__ short W2t[128 * 128];
  __shared__ short Ts[64 * 128];
  for (int i = threadIdx.x; i < 128 * 128; i += 256){
    int k = i >> 7, c = i & 127;
    W1t[c * 128 + k] = f2bf(W1[i]);
    W2t[c * 128 + k] = f2bf(W2[i]);
  }
  __syncthreads();

  const int lane = threadIdx.x & 63;
  const int wave = threadIdx.x >> 6;
  const int col0 = lane & 15;
  const int kg   = lane >> 4;

  bf16x8 B1f[8][4];
  #pragma unroll
  for (int ct = 0; ct < 8; ct++)
    #pragma unroll
    for (int s = 0; s < 4; s++)
      B1f[ct][s] = *(const bf16x8*)&W1t[(ct * 16 + col0) * 128 + s * 32 + kg * 8];

  float bs1[8], bs2[8], w3v[8];
  #pragma unroll
  for (int ct = 0; ct < 8; ct++){
    bs1[ct] = b1[ct * 16 + col0];
    bs2[ct] = b2[ct * 16 + col0];
    w3v[ct] = w3[ct * 16 + col0];
  }
  const float b3v = b3[0];

  const long tiles = ((long)M + 63) >> 6;
  for (long t = blockIdx.x; t < tiles; t += gridDim.x){
    const long rbase = t * 64 + wave * 16;
    const long arow  = rbase + col0;
    const float* Xp = X + (arow < M ? arow : 0) * D;

    bf16x8 Af[4];
    #pragma unroll
    for (int s = 0; s < 4; s++){
      const int kb = s * 32 + kg * 8;
      float4 lo = *(const float4*)(Xp + kb);
      float4 hi = *(const float4*)(Xp + kb + 4);
      bf16x8 a;
      a[0]=f2bf(lo.x); a[1]=f2bf(lo.y); a[2]=f2bf(lo.z); a[3]=f2bf(lo.w);
      a[4]=f2bf(hi.x); a[5]=f2bf(hi.y); a[6]=f2bf(hi.z); a[7]=f2bf(hi.w);
      Af[s] = a;
    }

    f32x4 acc[8];
    #pragma unroll
    for (int ct = 0; ct < 8; ct++){ acc[ct][0]=0.f; acc[ct][1]=0.f; acc[ct][2]=0.f; acc[ct][3]=0.f; }
    #pragma unroll
    for (int ct = 0; ct < 8; ct++)
      #pragma unroll
      for (int s = 0; s < 4; s++)
        acc[ct] = __builtin_amdgcn_mfma_f32_16x16x32_bf16(Af[s], B1f[ct][s], acc[ct], 0, 0, 0);

    #pragma unroll
    for (int ct = 0; ct < 8; ct++){
      const int c = ct * 16 + col0;
      #pragma unroll
      for (int r = 0; r < 4; r++){
        const int row = wave * 16 + kg * 4 + r;
        const int gg = (c >> 3) ^ (row & 7);
        Ts[row * 128 + gg * 8 + (c & 7)] = f2bf(siluf(acc[ct][r] + bs1[ct]));
      }
    }
    __syncthreads();

    const int row2 = wave * 16 + col0;
    bf16x8 A2f[4];
    #pragma unroll
    for (int s = 0; s < 4; s++){
      const int chunk = (s * 4 + kg) ^ (row2 & 7);
      A2f[s] = *(const bf16x8*)&Ts[row2 * 128 + chunk * 8];
    }
    __syncthreads();

    #pragma unroll
    for (int ct = 0; ct < 8; ct++){ acc[ct][0]=0.f; acc[ct][1]=0.f; acc[ct][2]=0.f; acc[ct][3]=0.f; }
    #pragma unroll
    for (int ct = 0; ct < 8; ct++){
      bf16x8 B2v[4];
      #pragma unroll
      for (int s = 0; s < 4; s++)
        B2v[s] = *(const bf16x8*)&W2t[(ct * 16 + col0) * 128 + s * 32 + kg * 8];
      #pragma unroll
      for (int s = 0; s < 4; s++)
        acc[ct] = __builtin_amdgcn_mfma_f32_16x16x32_bf16(A2f[s], B2v[s], acc[ct], 0, 0, 0);
    }

    #pragma unroll
    for (int r = 0; r < 4; r++){
      float vr = 0.f;
      #pragma unroll
      for (int ct = 0; ct < 8; ct++)
        vr += siluf(acc[ct][r] + bs2[ct]) * w3v[ct];
      #pragma unroll
      for (int off = 1; off < 16; off <<= 1) vr += __shfl_xor(vr, off, 64);
      const long orow = rbase + kg * 4 + r;
      if (col0 == 0 && orow < M) results[orow] += vr + b3v;
    }
  }
}

// ---------- CSR build ----------
__global__ void k_hist(const int* __restrict__ idx, int* __restrict__ cnt, int M)
{
  for (long i = (long)blockIdx.x * 256 + threadIdx.x; i < M; i += (long)gridDim.x * 256)
    atomicAdd(&cnt[idx[i]], 1);
}

__global__ void k_scan(const int* __restrict__ cnt, int* __restrict__ rowptr, int M)
{
  __shared__ int buf[1024];
  const int tid = threadIdx.x;
  const int PT = 16;
  int carry = 0;
  for (int base = 0; base < M; base += 1024 * PT){
    int loc[PT]; int s = 0;
    #pragma unroll
    for (int j = 0; j < PT; j++){
      int i = base + tid * PT + j;
      loc[j] = (i < M) ? cnt[i] : 0;
      s += loc[j];
    }
    buf[tid] = s; __syncthreads();
    for (int off = 1; off < 1024; off <<= 1){
      int t = (tid >= off) ? buf[tid - off] : 0;
      __syncthreads();
      buf[tid] += t;
      __syncthreads();
    }
    int run = buf[tid] - s + carry;
    carry += buf[1023];
    __syncthreads();
    #pragma unroll
    for (int j = 0; j < PT; j++){
      int i = base + tid * PT + j;
      if (i < M) rowptr[i] = run;
      run += loc[j];
    }
  }
  if (tid == 0) rowptr[M] = carry;
}

__global__ void k_fill(const int* __restrict__ idx, const int* __restrict__ rowptr,
                       int* __restrict__ cursor, int* __restrict__ ids, int M)
{
  for (long i = (long)blockIdx.x * 256 + threadIdx.x; i < M; i += (long)gridDim.x * 256){
    int sgm = idx[i];
    int pos = atomicAdd(&cursor[sgm], 1);
    ids[rowptr[sgm] + pos] = (int)i;
  }
}

// invD[eids[i]] = i; srcCSR[i] = srcA[eids[i]]
__global__ void k_invsrc(const int* __restrict__ eids, const int* __restrict__ srcA,
                         int* __restrict__ invD, int* __restrict__ srcCSR, int E_)
{
  for (long i = (long)blockIdx.x * 256 + threadIdx.x; i < E_; i += (long)gridDim.x * 256){
    int e = eids[i];
    invD[e] = (int)i;
    srcCSR[i] = srcA[e];
  }
}

// ---------- CSR gather-sum (atoms_rep) ----------
__global__ __launch_bounds__(256) void k_gather_sum(
    const float* __restrict__ X, const int* __restrict__ rowptr,
    const int* __restrict__ ids, float* __restrict__ Yat, int A_)
{
  const int lane = threadIdx.x & 63;
  const int wv   = threadIdx.x >> 6;
  for (long a = (long)blockIdx.x * 4 + wv; a < A_; a += (long)gridDim.x * 4){
    int beg = rowptr[a], end = rowptr[a + 1];
    float a0 = 0.f, a1 = 0.f;
    for (int i = beg; i < end; i++){
      const float* xp = X + (long)ids[i] * D;
      a0 += xp[lane]; a1 += xp[lane + 64];
    }
    Yat[a * D + lane] = a0; Yat[a * D + lane + 64] = a1;
  }
}

// ---------- CSR gather with rbf gate (readout scatter) ----------
__global__ __launch_bounds__(256) void k_gather_gate_sum(
    const float* __restrict__ X, const float* __restrict__ rbf,
    const float* __restrict__ Wr, const int* __restrict__ rowptr,
    const int* __restrict__ ids, float* __restrict__ Yat, int A_)
{
  __shared__ float Wrs[RBFD * D];
  for (int i = threadIdx.x; i < RBFD * D; i += 256) Wrs[i] = Wr[i];
  __syncthreads();
  const int lane = threadIdx.x & 63;
  const int wv   = threadIdx.x >> 6;
  for (long a = (long)blockIdx.x * 4 + wv; a < A_; a += (long)gridDim.x * 4){
    int beg = rowptr[a], end = rowptr[a + 1];
    float a0 = 0.f, a1 = 0.f;
    for (int i = beg; i < end; i++){
      long n = ids[i];
      const float* xp = X + n * D;
      const float* rb = rbf + n * RBFD;
      float g0 = 0.f, g1 = 0.f;
      #pragma unroll
      for (int r = 0; r < RBFD; r++){
        float rv = rb[r];
        g0 += rv * Wrs[r * D + lane];
        g1 += rv * Wrs[r * D + lane + 64];
      }
      a0 += xp[lane] * g0; a1 += xp[lane + 64] * g1;
    }
    Yat[a * D + lane] = a0; Yat[a * D + lane + 64] = a1;
  }
}

// ---------- fused attention v3: max-free softmax, bf16 col-pair streams, 4-edge MLP ----------
// lane owns cols (2*lane, 2*lane+1); head h = lane>>3; logit reduce = 3 shfls over 8 lanes.
__global__ __launch_bounds__(256) void k_attn(
    const unsigned short* __restrict__ q, const unsigned short* __restrict__ k,
    const unsigned short* __restrict__ v, const unsigned short* __restrict__ ek,
    const unsigned short* __restrict__ sw,
    const int* __restrict__ rowptr, const int* __restrict__ srcCSR,
    const float* __restrict__ rbf, const float* __restrict__ Wr,
    const int* __restrict__ batch,
    double* __restrict__ sums, double* __restrict__ sumsq,
    float* __restrict__ h, int Nn)
{
  __shared__ float Wrs[RBFD * D];
  for (int i = threadIdx.x; i < RBFD * D; i += 256) Wrs[i] = Wr[i];
  __syncthreads();
  const int lane = threadIdx.x & 63;
  const int wv   = threadIdx.x >> 6;
  for (long d = (long)blockIdx.x * 4 + wv; d < Nn; d += (long)gridDim.x * 4){
    const int beg = rowptr[d], end = rowptr[d + 1];
    const unsigned qp = *(const unsigned*)(q + d * D + 2 * lane);
    const float q0 = bflo(qp), q1 = bfhi(qp);
    float l = 0.f, a0 = 0.f, a1 = 0.f;
    for (int i = beg; i < end; i += 4){
      unsigned kk[4], vv[4], ee[4], ssw[4];
      #pragma unroll
      for (int j = 0; j < 4; j++){
        const long idx = (i + j < end) ? (long)(i + j) : (long)(end - 1);
        const long s = srcCSR[idx];
        kk[j]  = *(const unsigned*)(k  + s * D + 2 * lane);
        vv[j]  = *(const unsigned*)(v  + s * D + 2 * lane);
        ee[j]  = *(const unsigned*)(ek + idx * D + 2 * lane);
        ssw[j] = *(const unsigned*)(sw + idx * D + 2 * lane);
      }
      #pragma unroll
      for (int j = 0; j < 4; j++){
        const float valid = (i + j < end) ? 1.f : 0.f;
        float e0 = bflo(ee[j]), e1 = bfhi(ee[j]);
        float t = q0 * (bflo(kk[j]) + e0) + q1 * (bfhi(kk[j]) + e1);
        t += __shfl_xor(t, 1, 64);
        t += __shfl_xor(t, 2, 64);
        t += __shfl_xor(t, 4, 64);
        float w = __expf(t * 0.25f) * valid;
        float u0 = (bflo(vv[j]) + e0) * bflo(ssw[j]);
        float u1 = (bfhi(vv[j]) + e1) * bfhi(ssw[j]);
        l += w; a0 += w * u0; a1 += w * u1;
      }
    }
    const float inv = 1.f / (l + 1e-16f);
    a0 *= inv; a1 *= inv;
    // rbf gate (cols 2*lane, 2*lane+1)
    const float* rb = rbf + d * RBFD;
    float g0 = 0.f, g1 = 0.f;
    #pragma unroll
    for (int r = 0; r < RBFD; r++){
      float rv = rb[r];
      g0 += rv * Wrs[r * D + 2 * lane];
      g1 += rv * Wrs[r * D + 2 * lane + 1];
    }
    a0 *= g0; a1 *= g1;
    *(float2*)(h + d * D + 2 * lane) = make_float2(a0, a1);
    // graph-norm stats
    float ss = a0 + a1, qq = a0 * a0 + a1 * a1;
    #pragma unroll
    for (int off = 1; off < 64; off <<= 1){
      ss += __shfl_xor(ss, off, 64);
      qq += __shfl_xor(qq, off, 64);
    }
    if (lane == 0){
      int g = batch[d];
      atomicAdd(&sums[g], (double)ss);
      atomicAdd(&sumsq[g], (double)qq);
    }
  }
}

// ---------- graph norm ----------
__global__ void k_count(const int* __restrict__ batch, int* __restrict__ cnt, int M)
{
  for (long i = (long)blockIdx.x * 256 + threadIdx.x; i < M; i += (long)gridDim.x * 256)
    atomicAdd(&cnt[batch[i]], 1);
}

__global__ void k_norm_final(const double* __restrict__ sums, const double* __restrict__ sumsq,
                             const int* __restrict__ cnt, float* __restrict__ meanG,
                             float* __restrict__ rstdG)
{
  int g = threadIdx.x;
  double c = (double)cnt[g] * (double)D;
  double mean = sums[g] / c;
  double var = sumsq[g] / c - mean * mean;
  meanG[g] = (float)mean;
  rstdG[g] = (float)(1.0 / sqrt(var + 1e-8));
}

__global__ void k_final(const float* __restrict__ results, const int* __restrict__ ab,
                        float* __restrict__ out, int A_)
{
  int i = blockIdx.x * 256 + threadIdx.x;
  if (i < A_) atomicAdd(&out[ab[i]], results[i] / 3.0f);
}

// ---------- fold w2@we, b2@we ----------
__global__ void k_w2e(const float* __restrict__ w2, const float* __restrict__ we,
                      float* __restrict__ W2e)
{
  int i = blockIdx.x >> 7;
  int r = blockIdx.x & 127;
  int c = threadIdx.x;
  const float* w2p = w2 + (size_t)i * D * D + (size_t)r * D;
  const float* wep = we + (size_t)i * D * D;
  float acc = 0.f;
  for (int j = 0; j < D; j++) acc += w2p[j] * wep[j * D + c];
  W2e[(size_t)i * D * D + (size_t)r * D + c] = acc;
}

__global__ void k_b2e(const float* __restrict__ b2, const float* __restrict__ we,
                      float* __restrict__ B2e)
{
  int i = blockIdx.x; int c = threadIdx.x;
  float acc = 0.f;
  for (int j = 0; j < D; j++) acc += b2[(size_t)i * D + j] * we[(size_t)i * D * D + j * D + c];
  B2e[(size_t)i * D + c] = acc;
}

extern "C" void kernel_launch(void* const* d_in, const int* in_sizes, int n_in,
                              void* d_out, int out_size, void* d_ws, size_t ws_size,
                              hipStream_t stream)
{
  const float* x          = (const float*)d_in[0];
  const float* node_rbf   = (const float*)d_in[1];
  const float* edge_sbf   = (const float*)d_in[2];
  const int*   edge_index = (const int*)d_in[3];
  const int*   pair_idx   = (const int*)d_in[4];
  const int*   eidx0      = (const int*)d_in[5];
  const int*   atom_batch = (const int*)d_in[6];
  const int*   batch      = (const int*)d_in[7];
  const float* edgenn_w1  = (const float*)d_in[8];
  const float* edgenn_b1  = (const float*)d_in[9];
  const float* edgenn_w2  = (const float*)d_in[10];
  const float* edgenn_b2  = (const float*)d_in[11];
  const float* conv_wq    = (const float*)d_in[12];
  const float* conv_wk    = (const float*)d_in[13];
  const float* conv_wv    = (const float*)d_in[14];
  const float* conv_we    = (const float*)d_in[15];
  const float* conv_wsbf  = (const float*)d_in[16];
  const float* conv_bsbf  = (const float*)d_in[17];
  const float* conv_wrbf  = (const float*)d_in[18];
  const float* dense_w    = (const float*)d_in[19];
  const float* dense_b    = (const float*)d_in[20];
  const float* bf_w       = (const float*)d_in[21];
  const float* bf_b       = (const float*)d_in[22];
  const float* af_w       = (const float*)d_in[23];
  const float* af_b       = (const float*)d_in[24];
  const float* read_wrbf  = (const float*)d_in[25];
  const float* read_w1    = (const float*)d_in[26];
  const float* read_b1    = (const float*)d_in[27];
  const float* read_w2    = (const float*)d_in[28];
  const float* read_b2    = (const float*)d_in[29];
  const float* read_w3    = (const float*)d_in[30];
  const float* read_b3    = (const float*)d_in[31];

  const int N = in_sizes[0] / D;
  const int E = in_sizes[4];
  const int A = in_sizes[6];
  const int G = out_size;

  char* p = (char*)d_ws;
  auto carve = [&](size_t bytes)->char*{ char* r = p; p += (bytes + 255) & ~(size_t)255; return r; };
  unsigned short* ekb  = (unsigned short*)carve((size_t)E * D * 2);  // ek bf16 (CSR order)
  unsigned short* swb  = (unsigned short*)carve((size_t)E * D * 2);  // sw bf16 (CSR order)
  unsigned short* qb   = (unsigned short*)carve((size_t)N * D * 2);
  unsigned short* kb   = (unsigned short*)carve((size_t)N * D * 2);
  unsigned short* vb   = (unsigned short*)carve((size_t)N * D * 2);
  float*    hbuf    = (float*)carve((size_t)N * D * 4);
  float*    ping0   = (float*)carve((size_t)N * D * 4);
  float*    ping1   = (float*)carve((size_t)N * D * 4);
  float*    bufAtoms= (float*)carve((size_t)A * D * 4);
  float*    results = (float*)carve((size_t)A * 4);
  double*   sumG    = (double*)carve((size_t)G * 8);
  double*   sumsqG  = (double*)carve((size_t)G * 8);
  int*      cntG    = (int*)carve((size_t)G * 4);
  float*    meanG   = (float*)carve((size_t)G * 4);
  float*    rstdG   = (float*)carve((size_t)G * 4);
  float*    W2e     = (float*)carve((size_t)LAYERS * D * D * 4);
  float*    B2e     = (float*)carve((size_t)LAYERS * D * 4);
  int*      rowptrD = (int*)carve((size_t)(N + 1) * 4);
  int*      eidsD   = (int*)carve((size_t)E * 4);
  int*      invD    = (int*)carve((size_t)E * 4);
  int*      srcCSR  = (int*)carve((size_t)E * 4);
  int*      cntD    = (int*)carve((size_t)N * 4);
  int*      rowptrA = (int*)carve((size_t)(A + 1) * 4);
  int*      idsA    = (int*)carve((size_t)N * 4);
  int*      cntA    = (int*)carve((size_t)A * 4);

  const int* srcA = edge_index;
  const int* dstA = edge_index + E;

  auto ew_grid = [](long total){ long b = (total + 255) / 256; return (int)(b < 4096 ? b : 4096); };
  auto gemm_grid = [](int M){ long t = ((long)M + 63) / 64; return (int)(t < 1024 ? t : 1024); };
  const int gridAttn = (N + 3) / 4;
  const int gridAtom = (A + 3) / 4;

  // ---- one-time setup ----
  hipMemsetAsync(cntG, 0, (size_t)G * 4, stream);
  hipMemsetAsync(results, 0, (size_t)A * 4, stream);
  hipMemsetAsync(d_out, 0, (size_t)G * 4, stream);
  k_count<<<ew_grid(N), 256, 0, stream>>>(batch, cntG, N);
  k_w2e<<<LAYERS * D, D, 0, stream>>>(edgenn_w2, conv_we, W2e);
  k_b2e<<<LAYERS, D, 0, stream>>>(edgenn_b2, conv_we, B2e);
  // CSR by dst (edges)
  hipMemsetAsync(cntD, 0, (size_t)N * 4, stream);
  k_hist<<<ew_grid(E), 256, 0, stream>>>(dstA, cntD, E);
  k_scan<<<1, 1024, 0, stream>>>(cntD, rowptrD, N);
  hipMemsetAsync(cntD, 0, (size_t)N * 4, stream);
  k_fill<<<ew_grid(E), 256, 0, stream>>>(dstA, rowptrD, cntD, eidsD, E);
  k_invsrc<<<ew_grid(E), 256, 0, stream>>>(eidsD, srcA, invD, srcCSR, E);
  // CSR by atom (nodes)
  hipMemsetAsync(cntA, 0, (size_t)A * 4, stream);
  k_hist<<<ew_grid(N), 256, 0, stream>>>(eidx0, cntA, N);
  k_scan<<<1, 1024, 0, stream>>>(cntA, rowptrA, A);
  hipMemsetAsync(cntA, 0, (size_t)A * 4, stream);
  k_fill<<<ew_grid(N), 256, 0, stream>>>(eidx0, rowptrA, cntA, idsA, N);

  auto readout = [&](int i, const float* hb){
    k_gather_gate_sum<<<gridAtom, 256, 0, stream>>>(hb, node_rbf, read_wrbf + (size_t)i * RBFD * D,
                                                    rowptrA, idsA, bufAtoms, A);
    k_read2<<<gemm_grid(A), 256, 0, stream>>>(bufAtoms,
        read_w1 + (size_t)i*D*D, read_b1 + (size_t)i*D,
        read_w2 + (size_t)i*D*D, read_b2 + (size_t)i*D,
        read_w3 + (size_t)i*D, read_b3 + i, results, A);
  };

  readout(0, x);

  const float* cur = x;
  float* pp[2] = {ping0, ping1};
  for (int i = 0; i < LAYERS; i++){
    float* nxt = pp[i & 1];
    const size_t oDD = (size_t)i * D * D;
    // atoms_rep = segsum(cur, eidx0)  (CSR gather)
    k_gather_sum<<<gridAtom, 256, 0, stream>>>(cur, rowptrA, idsA, bufAtoms, A);
    // ek = silu(atoms_rep[pair_idx]@w1+b1) @ (w2@we) + b2@we  -> bf16, CSR order
    k_gemm2<<<gemm_grid(E),256,0,stream>>>(bufAtoms, pair_idx, edgenn_w1 + oDD, edgenn_b1 + (size_t)i*D,
                                           W2e + oDD, B2e + (size_t)i*D, ekb, invD, E);
    // q, k, v -> bf16
    k_gemm<D,0,false,false,false,false,true><<<gemm_grid(N),256,0,stream>>>(cur, nullptr, conv_wq + oDD, nullptr, nullptr, qb, nullptr, N);
    k_gemm<D,0,false,false,false,false,true><<<gemm_grid(N),256,0,stream>>>(cur, nullptr, conv_wk + oDD, nullptr, nullptr, kb, nullptr, N);
    k_gemm<D,0,false,false,false,false,true><<<gemm_grid(N),256,0,stream>>>(cur, nullptr, conv_wv + oDD, nullptr, nullptr, vb, nullptr, N);
    // sw = edge_sbf @ wsbf + bsbf -> bf16, CSR order
    k_gemm<SBFD,0,false,true,false,true,true><<<gemm_grid(E),256,0,stream>>>(edge_sbf, nullptr, conv_wsbf + (size_t)i*SBFD*D, conv_bsbf + (size_t)i*D, nullptr, swb, invD, E);
    // fused attention + rbf gate + stats -> hbuf
    hipMemsetAsync(sumG, 0, (size_t)G * 16, stream);   // sumG + sumsqG (adjacent)
    k_attn<<<gridAttn, 256, 0, stream>>>(qb, kb, vb, ekb, swb, rowptrD, srcCSR,
                                         node_rbf, conv_wrbf + (size_t)i*RBFD*D, batch,
                                         sumG, sumsqG, hbuf, N);
    k_norm_final<<<1, G, 0, stream>>>(sumG, sumsqG, cntG, meanG, rstdG);
    // bf residual block (absorbs norm-apply), in place on hbuf
    k_res2<true><<<gemm_grid(N),256,0,stream>>>(hbuf, bf_w + (size_t)i*2*D*D, bf_b + (size_t)i*2*D,
                                                bf_w + (size_t)i*2*D*D + D*D, bf_b + (size_t)i*2*D + D,
                                                batch, meanG, rstdG, hbuf, N);
    // dense + res0
    k_gemm<D,1,false,true,true,false,false><<<gemm_grid(N),256,0,stream>>>(hbuf, nullptr, dense_w + oDD, dense_b + (size_t)i*D, cur, nxt, nullptr, N);
    // af residual blocks, in place on nxt
    k_res2<false><<<gemm_grid(N),256,0,stream>>>(nxt, af_w + (size_t)i*4*D*D,         af_b + (size_t)i*4*D,
                                                 af_w + (size_t)i*4*D*D + D*D,       af_b + (size_t)i*4*D + D,
                                                 nullptr, nullptr, nullptr, nxt, N);
    k_res2<false><<<gemm_grid(N),256,0,stream>>>(nxt, af_w + (size_t)i*4*D*D + 2*D*D, af_b + (size_t)i*4*D + 2*D,
                                                 af_w + (size_t)i*4*D*D + 3*D*D,     af_b + (size_t)i*4*D + 3*D,
                                                 nullptr, nullptr, nullptr, nxt, N);
    // readout
    readout(i + 1, nxt);
    cur = nxt;
  }
  k_final<<<(A + 255) / 256, 256, 0, stream>>>(results, atom_batch, (float*)d_out, A);
}